// Round 4
// baseline (715.148 us; speedup 1.0000x reference)
//
#include <hip/hip_runtime.h>
#include <math.h>

#define F 128
#define NLAYERS 2

typedef __attribute__((ext_vector_type(8))) short bf16x8s;
typedef __attribute__((ext_vector_type(8))) unsigned short u16x8;
typedef __attribute__((ext_vector_type(4))) float f32x4;

__device__ __forceinline__ float sigmoidf_(float x) { return 1.0f / (1.0f + expf(-x)); }

__device__ __forceinline__ unsigned short f2bf(float f) {
    unsigned int u = __float_as_uint(f);
    u += 0x7fffu + ((u >> 16) & 1u);  // RNE
    return (unsigned short)(u >> 16);
}
__device__ __forceinline__ float bf2f(unsigned short s) {
    return __uint_as_float(((unsigned int)s) << 16);
}

// ---------------------------------------------------------------------------
// Weight pack: f32 [L][3][256][128] -> bf16 k-octet layout.
//  W1b [L][64][256][8]: gates (r|u) as 256 cols, K=512 parts (x,h,agg_x,agg_h)
//  W2b [L][64][128][8]: gate c, K parts (x, rh, agg_x, agg_rh)
// ---------------------------------------------------------------------------
__global__ void pack_w_bf16(const float* __restrict__ Ws, const float* __restrict__ Wn,
                            unsigned short* __restrict__ W1b, unsigned short* __restrict__ W2b) {
    int t = blockIdx.x * blockDim.x + threadIdx.x;
    const int n1 = 2 * 64 * 256 * 8;  // 262144
    if (t < n1) {
        int j = t & 7, n = (t >> 3) & 255, ko = (t >> 11) & 63, l = t >> 17;
        int k = ko * 8 + j;
        int p = k >> 7, r = k & 127, g = n >> 7, c = n & 127;
        const float* W = (p < 2) ? Ws : Wn;
        W1b[t] = f2bf(W[(((l * 3 + g) * 256) + ((p & 1) * 128 + r)) * 128 + c]);
    } else {
        int t2 = t - n1;
        if (t2 >= 2 * 64 * 128 * 8) return;
        int j = t2 & 7, n = (t2 >> 3) & 127, ko = (t2 >> 10) & 63, l = t2 >> 16;
        int k = ko * 8 + j;
        int p = k >> 7, r = k & 127;
        const float* W = (p < 2) ? Ws : Wn;
        W2b[t2] = f2bf(W[(((l * 3 + 2) * 256) + ((p & 1) * 128 + r)) * 128 + n]);
    }
}

// Fused f32 -> bf16 interleave: x -> xh0[:,0:128], h0 -> xh0[:,128:256],
// h1 -> xh1[:,128:256]. Each t handles 4 floats.
__global__ void cvt_all(const float* __restrict__ x, const float* __restrict__ hidden,
                        unsigned short* __restrict__ xh0, unsigned short* __restrict__ xh1,
                        int n4, size_t NF) {
    int t = blockIdx.x * blockDim.x + threadIdx.x;
    const float* in;
    unsigned short* out;
    int tt;
    if (t < n4) { in = x; out = xh0; tt = t; }
    else if (t < 2 * n4) { in = hidden; out = xh0 + 128; tt = t - n4; }
    else if (t < 3 * n4) { in = hidden + NF; out = xh1 + 128; tt = t - 2 * n4; }
    else return;
    float4 v = reinterpret_cast<const float4*>(in)[tt];
    ushort4 o;
    o.x = f2bf(v.x); o.y = f2bf(v.y); o.z = f2bf(v.z); o.w = f2bf(v.w);
    *reinterpret_cast<ushort4*>(out + (((size_t)(tt >> 5)) << 8) + ((tt & 31) << 2)) = o;
}

// ---------------------------------------------------------------------------
// CSR build
// ---------------------------------------------------------------------------
__global__ void hist_dst(const int* __restrict__ dst, int* __restrict__ cnt, int E) {
    int e = blockIdx.x * blockDim.x + threadIdx.x;
    if (e < E) atomicAdd(&cnt[dst[e]], 1);
}

__global__ __launch_bounds__(1024) void scan_blk(const int* __restrict__ cnt,
                                                 int* __restrict__ offs,
                                                 int* __restrict__ bsum, int n) {
    __shared__ int wsum[16];
    int tid = threadIdx.x, lane = tid & 63, wid = tid >> 6;
    int i = blockIdx.x * 1024 + tid;
    int v = (i < n) ? cnt[i] : 0;
    int incl = v;
#pragma unroll
    for (int off = 1; off < 64; off <<= 1) {
        int t = __shfl_up(incl, off, 64);
        if (lane >= off) incl += t;
    }
    if (lane == 63) wsum[wid] = incl;
    __syncthreads();
    if (wid == 0) {
        int s = (lane < 16) ? wsum[lane] : 0;
#pragma unroll
        for (int off = 1; off < 16; off <<= 1) {
            int t = __shfl_up(s, off, 64);
            if (lane >= off) s += t;
        }
        if (lane < 16) wsum[lane] = s;
    }
    __syncthreads();
    int wbase = (wid > 0) ? wsum[wid - 1] : 0;
    if (i < n) offs[i] = wbase + incl - v;
    if (tid == 1023) bsum[blockIdx.x] = wbase + incl;
}

__global__ __launch_bounds__(1024) void scan_tops(int* __restrict__ bsum, int nb,
                                                  int* __restrict__ total_out) {
    __shared__ int wsum[16];
    int tid = threadIdx.x, lane = tid & 63, wid = tid >> 6;
    int v = (tid < nb) ? bsum[tid] : 0;
    int incl = v;
#pragma unroll
    for (int off = 1; off < 64; off <<= 1) {
        int t = __shfl_up(incl, off, 64);
        if (lane >= off) incl += t;
    }
    if (lane == 63) wsum[wid] = incl;
    __syncthreads();
    if (wid == 0) {
        int s = (lane < 16) ? wsum[lane] : 0;
#pragma unroll
        for (int off = 1; off < 16; off <<= 1) {
            int t = __shfl_up(s, off, 64);
            if (lane >= off) s += t;
        }
        if (lane < 16) wsum[lane] = s;
    }
    __syncthreads();
    int wbase = (wid > 0) ? wsum[wid - 1] : 0;
    if (tid < nb) bsum[tid] = wbase + incl - v;
    if (tid == 1023) *total_out = wbase + incl;
}

__global__ __launch_bounds__(1024) void scan_add(const int* __restrict__ bsum,
                                                 int* __restrict__ offs,
                                                 int* __restrict__ cursor, int n) {
    int i = blockIdx.x * 1024 + threadIdx.x;
    if (i >= n) return;
    int o = offs[i] + bsum[blockIdx.x];
    offs[i] = o;
    cursor[i] = o;
}

__global__ void scatter_edges(const int* __restrict__ src, const int* __restrict__ dst,
                              const float* __restrict__ ew, int* __restrict__ cursor,
                              int2* __restrict__ es, int E) {
    int e = blockIdx.x * blockDim.x + threadIdx.x;
    if (e >= E) return;
    int d = dst[e];
    int p = atomicAdd(&cursor[d], 1);
    es[p] = make_int2(src[e], __float_as_int(ew[e]));
}

// ---------------------------------------------------------------------------
// FUSED kernel 1 (gates r,u): per block of 64 nodes,
//  phase A: CSR gather over interleaved xh[N][256] -> LDS AGG (XOR-swizzled),
//           aggx half also written to global (needed by gate c kernel).
//  phase B: GEMM 64x256, K=512; A parts 0/1 (x,h) staged from global xh,
//           parts 2/3 (aggx,aggh) read from LDS AGG. B = W1b k-octet layout.
//  epilogue: col<128 -> rhb = bf16(sigmoid*h); col>=128 -> u = sigmoid (f32)
// LDS: AGG 32KB + Als 8KB + Bls 32KB = 72KB -> 2 blocks/CU.
// ---------------------------------------------------------------------------
__global__ __launch_bounds__(256) void fused_ru(
    const unsigned short* __restrict__ XH,
    const int2* __restrict__ es, const int* __restrict__ offs,
    const unsigned short* __restrict__ Wb, const float* __restrict__ bias,
    const float* __restrict__ hfull,
    unsigned short* __restrict__ aggx_out,
    unsigned short* __restrict__ rhb, float* __restrict__ u, int N) {
    __shared__ __align__(16) unsigned short AGG[64 * 256];        // 32KB
    __shared__ __align__(16) unsigned short Als[2][4 * 64 * 8];   // 8KB
    __shared__ __align__(16) unsigned short Bls[2][4 * 256 * 8];  // 32KB

    int tid = threadIdx.x;
    int row0 = blockIdx.x * 64;
    int lane64 = tid & 63, w = tid >> 6;
    int lane32 = tid & 31, grp = tid >> 5;

    int growA = row0 + lane64;
    if (growA >= N) growA = N - 1;

    // Prefetch first GEMM stage (ks=0) while gather runs.
    {
        const unsigned short* ga = XH + (size_t)growA * 256 + (w << 3);
        __builtin_amdgcn_global_load_lds(
            (const __attribute__((address_space(1))) void*)ga,
            (__attribute__((address_space(3))) void*)&Als[0][((w << 6) + lane64) << 3], 16, 0, 0);
#pragma unroll
        for (int r = 0; r < 4; ++r) {
            int idx = (r << 8) + tid;
            int q = idx >> 8, n = idx & 255;
            const unsigned short* gb = Wb + ((size_t)(q * 256 + n) << 3);
            __builtin_amdgcn_global_load_lds(
                (const __attribute__((address_space(1))) void*)gb,
                (__attribute__((address_space(3))) void*)&Bls[0][((q << 8) + n) << 3], 16, 0, 0);
        }
    }

    // ---- Phase A: gather. 8 groups of 32 lanes; each group 8 nodes. ----
    int loff = lane32 << 3;
    for (int ln = grp; ln < 64; ln += 8) {
        int node = row0 + ln;
        float a0[8] = {0, 0, 0, 0, 0, 0, 0, 0};
        float a1[8] = {0, 0, 0, 0, 0, 0, 0, 0};
        if (node < N) {
            int beg = offs[node], end = offs[node + 1];
            int i = beg;
            for (; i + 3 < end; i += 4) {
                int2 e0 = es[i], e1 = es[i + 1], e2 = es[i + 2], e3 = es[i + 3];
                u16x8 v0 = *reinterpret_cast<const u16x8*>(XH + (((size_t)e0.x) << 8) + loff);
                u16x8 v1 = *reinterpret_cast<const u16x8*>(XH + (((size_t)e1.x) << 8) + loff);
                u16x8 v2 = *reinterpret_cast<const u16x8*>(XH + (((size_t)e2.x) << 8) + loff);
                u16x8 v3 = *reinterpret_cast<const u16x8*>(XH + (((size_t)e3.x) << 8) + loff);
                float w0 = __int_as_float(e0.y), w1 = __int_as_float(e1.y);
                float w2 = __int_as_float(e2.y), w3 = __int_as_float(e3.y);
#pragma unroll
                for (int j = 0; j < 8; ++j) {
                    a0[j] += w0 * bf2f(v0[j]);
                    a1[j] += w1 * bf2f(v1[j]);
                    a0[j] += w2 * bf2f(v2[j]);
                    a1[j] += w3 * bf2f(v3[j]);
                }
            }
            for (; i < end; ++i) {
                int2 e0 = es[i];
                float w0 = __int_as_float(e0.y);
                u16x8 v0 = *reinterpret_cast<const u16x8*>(XH + (((size_t)e0.x) << 8) + loff);
#pragma unroll
                for (int j = 0; j < 8; ++j) a0[j] += w0 * bf2f(v0[j]);
            }
        }
        u16x8 o;
#pragma unroll
        for (int j = 0; j < 8; ++j) o[j] = f2bf(a0[j] + a1[j]);
        // LDS write, XOR-swizzled within the 256-el row (8-el granules).
        int sidx = ln * 256 + ((lane32 << 3) ^ ((ln & 7) << 3));
        *reinterpret_cast<u16x8*>(&AGG[sidx]) = o;
        // aggx half -> global for the gate-c kernel.
        if (node < N && lane32 < 16)
            *reinterpret_cast<u16x8*>(aggx_out + (((size_t)node) << 7) + (lane32 << 3)) = o;
    }
    __syncthreads();

    // ---- Phase B: GEMM 64 x 256, K = 512. ----
    int wrow = (w & 1) << 5;        // 0 / 32
    int wcol = (w >> 1) << 7;       // 0 / 128
    int quad = lane64 >> 4, l16 = lane64 & 15;

    f32x4 acc[2][8];
    const f32x4 z4 = {0.f, 0.f, 0.f, 0.f};
#pragma unroll
    for (int mt = 0; mt < 2; ++mt)
#pragma unroll
        for (int nt = 0; nt < 8; ++nt) acc[mt][nt] = z4;

    int buf = 0;
    for (int ks = 0; ks < 512; ks += 32, buf ^= 1) {
        int nk = ks + 32;
        if (nk < 512) {
#pragma unroll
            for (int r = 0; r < 4; ++r) {
                int idx = (r << 8) + tid;
                int q = idx >> 8, n = idx & 255;
                int koG = (nk >> 3) + q;
                const unsigned short* gb = Wb + ((size_t)(koG * 256 + n) << 3);
                __builtin_amdgcn_global_load_lds(
                    (const __attribute__((address_space(1))) void*)gb,
                    (__attribute__((address_space(3))) void*)&Bls[buf ^ 1][((q << 8) + n) << 3], 16, 0, 0);
            }
            if (nk < 256) {
                const unsigned short* ga = XH + (size_t)growA * 256 + nk + (w << 3);
                __builtin_amdgcn_global_load_lds(
                    (const __attribute__((address_space(1))) void*)ga,
                    (__attribute__((address_space(3))) void*)&Als[buf ^ 1][((w << 6) + lane64) << 3], 16, 0, 0);
            }
        }

        bf16x8s af[2], bfr[8];
        if (ks < 256) {
#pragma unroll
            for (int mt = 0; mt < 2; ++mt)
                af[mt] = *reinterpret_cast<const bf16x8s*>(
                    &Als[buf][((quad << 6) + wrow + (mt << 4) + l16) << 3]);
        } else {
            int colk = (ks - 256) + (quad << 3);
#pragma unroll
            for (int mt = 0; mt < 2; ++mt) {
                int row = wrow + (mt << 4) + l16;
                af[mt] = *reinterpret_cast<const bf16x8s*>(
                    &AGG[row * 256 + (colk ^ ((row & 7) << 3))]);
            }
        }
#pragma unroll
        for (int nt = 0; nt < 8; ++nt)
            bfr[nt] = *reinterpret_cast<const bf16x8s*>(
                &Bls[buf][((quad << 8) + wcol + (nt << 4) + l16) << 3]);
#pragma unroll
        for (int mt = 0; mt < 2; ++mt)
#pragma unroll
            for (int nt = 0; nt < 8; ++nt)
                acc[mt][nt] = __builtin_amdgcn_mfma_f32_16x16x32_bf16(
                    af[mt], bfr[nt], acc[mt][nt], 0, 0, 0);
        __syncthreads();
    }

    // ---- Epilogue (mode 0) ----
#pragma unroll
    for (int mt = 0; mt < 2; ++mt) {
#pragma unroll
        for (int reg = 0; reg < 4; ++reg) {
            int row = row0 + wrow + (mt << 4) + (quad << 2) + reg;
            if (row >= N) continue;
#pragma unroll
            for (int nt = 0; nt < 8; ++nt) {
                int col = wcol + (nt << 4) + l16;
                float val = acc[mt][nt][reg] + bias[col];
                float sg = sigmoidf_(val);
                int c = col & 127;
                size_t o = ((size_t)row << 7) + c;
                if (col < 128)
                    rhb[o] = f2bf(sg * hfull[o]);   // rh = r*h (bf16)
                else
                    u[o] = sg;                       // u (f32)
            }
        }
    }
}

// ---------------------------------------------------------------------------
// FUSED kernel 2 (gate c): per block of 64 nodes,
//  phase A: CSR gather over rhb[N][128] -> LDS AGG (XOR-swizzled).
//  phase B: GEMM 64x128, K=512; parts 0..2 (x, rh, aggx) staged from global,
//           part 3 (agg_rh) from LDS. B = W2b k-octet layout.
//  epilogue: c = sigmoid; hn = u*h+(1-u)*c -> outf (+outf2); outb = bf16(hn)
//            with row shift obsh (8 -> next xh cols 0:128, 7 -> plain 128).
// LDS: AGG 16KB + Als 8KB + Bls 16KB = 40KB -> 4 blocks/CU.
// ---------------------------------------------------------------------------
__global__ __launch_bounds__(256) void fused_c(
    const unsigned short* __restrict__ XH, const unsigned short* __restrict__ RHB,
    const unsigned short* __restrict__ AGGX,
    const int2* __restrict__ es, const int* __restrict__ offs,
    const unsigned short* __restrict__ Wb, const float* __restrict__ bias,
    const float* __restrict__ hfull, const float* __restrict__ uin,
    unsigned short* __restrict__ outb, float* __restrict__ outf,
    float* __restrict__ outf2, int obsh, int N) {
    __shared__ __align__(16) unsigned short AGG[64 * 128];        // 16KB
    __shared__ __align__(16) unsigned short Als[2][4 * 64 * 8];   // 8KB
    __shared__ __align__(16) unsigned short Bls[2][4 * 128 * 8];  // 16KB

    int tid = threadIdx.x;
    int row0 = blockIdx.x * 64;
    int lane64 = tid & 63, w = tid >> 6;
    int lane32 = tid & 31, grp = tid >> 5;

    int growA = row0 + lane64;
    if (growA >= N) growA = N - 1;

    // Prefetch first GEMM stage (ks=0: part 0 = x from XH).
    {
        const unsigned short* ga = XH + (size_t)growA * 256 + (w << 3);
        __builtin_amdgcn_global_load_lds(
            (const __attribute__((address_space(1))) void*)ga,
            (__attribute__((address_space(3))) void*)&Als[0][((w << 6) + lane64) << 3], 16, 0, 0);
#pragma unroll
        for (int r = 0; r < 2; ++r) {
            int idx = (r << 8) + tid;
            int q = idx >> 7, n = idx & 127;
            const unsigned short* gb = Wb + ((size_t)(q * 128 + n) << 3);
            __builtin_amdgcn_global_load_lds(
                (const __attribute__((address_space(1))) void*)gb,
                (__attribute__((address_space(3))) void*)&Bls[0][((q << 7) + n) << 3], 16, 0, 0);
        }
    }

    // ---- Phase A: gather rh (128 cols, 8B/lane). ----
    int loff = lane32 << 2;
    for (int ln = grp; ln < 64; ln += 8) {
        int node = row0 + ln;
        float p0[4] = {0, 0, 0, 0}, p1[4] = {0, 0, 0, 0};
        if (node < N) {
            int beg = offs[node], end = offs[node + 1];
            int i = beg;
            for (; i + 3 < end; i += 4) {
                int2 e0 = es[i], e1 = es[i + 1], e2 = es[i + 2], e3 = es[i + 3];
                ushort4 x0 = *reinterpret_cast<const ushort4*>(RHB + (((size_t)e0.x) << 7) + loff);
                ushort4 x1 = *reinterpret_cast<const ushort4*>(RHB + (((size_t)e1.x) << 7) + loff);
                ushort4 x2 = *reinterpret_cast<const ushort4*>(RHB + (((size_t)e2.x) << 7) + loff);
                ushort4 x3 = *reinterpret_cast<const ushort4*>(RHB + (((size_t)e3.x) << 7) + loff);
                float w0 = __int_as_float(e0.y), w1 = __int_as_float(e1.y);
                float w2 = __int_as_float(e2.y), w3 = __int_as_float(e3.y);
                p0[0] += w0 * bf2f(x0.x); p0[1] += w0 * bf2f(x0.y);
                p0[2] += w0 * bf2f(x0.z); p0[3] += w0 * bf2f(x0.w);
                p1[0] += w1 * bf2f(x1.x); p1[1] += w1 * bf2f(x1.y);
                p1[2] += w1 * bf2f(x1.z); p1[3] += w1 * bf2f(x1.w);
                p0[0] += w2 * bf2f(x2.x); p0[1] += w2 * bf2f(x2.y);
                p0[2] += w2 * bf2f(x2.z); p0[3] += w2 * bf2f(x2.w);
                p1[0] += w3 * bf2f(x3.x); p1[1] += w3 * bf2f(x3.y);
                p1[2] += w3 * bf2f(x3.z); p1[3] += w3 * bf2f(x3.w);
            }
            for (; i < end; ++i) {
                int2 e0 = es[i];
                float w0 = __int_as_float(e0.y);
                ushort4 x0 = *reinterpret_cast<const ushort4*>(RHB + (((size_t)e0.x) << 7) + loff);
                p0[0] += w0 * bf2f(x0.x); p0[1] += w0 * bf2f(x0.y);
                p0[2] += w0 * bf2f(x0.z); p0[3] += w0 * bf2f(x0.w);
            }
        }
        ushort4 o;
        o.x = f2bf(p0[0] + p1[0]); o.y = f2bf(p0[1] + p1[1]);
        o.z = f2bf(p0[2] + p1[2]); o.w = f2bf(p0[3] + p1[3]);
        int sidx = ln * 128 + ((lane32 << 2) ^ ((ln & 7) << 3));
        *reinterpret_cast<ushort4*>(&AGG[sidx]) = o;
    }
    __syncthreads();

    // ---- Phase B: GEMM 64 x 128, K = 512. ----
    int wrow = (w & 1) << 5;
    int wcol = (w >> 1) << 6;
    int quad = lane64 >> 4, l16 = lane64 & 15;

    f32x4 acc[2][4];
    const f32x4 z4 = {0.f, 0.f, 0.f, 0.f};
#pragma unroll
    for (int mt = 0; mt < 2; ++mt)
#pragma unroll
        for (int nt = 0; nt < 4; ++nt) acc[mt][nt] = z4;

    int buf = 0;
    for (int ks = 0; ks < 512; ks += 32, buf ^= 1) {
        int nk = ks + 32;
        if (nk < 512) {
#pragma unroll
            for (int r = 0; r < 2; ++r) {
                int idx = (r << 8) + tid;
                int q = idx >> 7, n = idx & 127;
                int koG = (nk >> 3) + q;
                const unsigned short* gb = Wb + ((size_t)(koG * 128 + n) << 3);
                __builtin_amdgcn_global_load_lds(
                    (const __attribute__((address_space(1))) void*)gb,
                    (__attribute__((address_space(3))) void*)&Bls[buf ^ 1][((q << 7) + n) << 3], 16, 0, 0);
            }
            if (nk < 384) {
                int p = nk >> 7;
                const unsigned short* ga =
                    (p == 0) ? (XH + (size_t)growA * 256 + (nk & 127) + (w << 3))
                  : (p == 1) ? (RHB + (size_t)growA * 128 + (nk & 127) + (w << 3))
                             : (AGGX + (size_t)growA * 128 + (nk & 127) + (w << 3));
                __builtin_amdgcn_global_load_lds(
                    (const __attribute__((address_space(1))) void*)ga,
                    (__attribute__((address_space(3))) void*)&Als[buf ^ 1][((w << 6) + lane64) << 3], 16, 0, 0);
            }
        }

        bf16x8s af[2], bfr[4];
        if (ks < 384) {
#pragma unroll
            for (int mt = 0; mt < 2; ++mt)
                af[mt] = *reinterpret_cast<const bf16x8s*>(
                    &Als[buf][((quad << 6) + wrow + (mt << 4) + l16) << 3]);
        } else {
            int colk = (ks - 384) + (quad << 3);
#pragma unroll
            for (int mt = 0; mt < 2; ++mt) {
                int row = wrow + (mt << 4) + l16;
                af[mt] = *reinterpret_cast<const bf16x8s*>(
                    &AGG[row * 128 + (colk ^ ((row & 7) << 3))]);
            }
        }
#pragma unroll
        for (int nt = 0; nt < 4; ++nt)
            bfr[nt] = *reinterpret_cast<const bf16x8s*>(
                &Bls[buf][((quad << 7) + wcol + (nt << 4) + l16) << 3]);
#pragma unroll
        for (int mt = 0; mt < 2; ++mt)
#pragma unroll
            for (int nt = 0; nt < 4; ++nt)
                acc[mt][nt] = __builtin_amdgcn_mfma_f32_16x16x32_bf16(
                    af[mt], bfr[nt], acc[mt][nt], 0, 0, 0);
        __syncthreads();
    }

    // ---- Epilogue (mode 1) ----
#pragma unroll
    for (int mt = 0; mt < 2; ++mt) {
#pragma unroll
        for (int reg = 0; reg < 4; ++reg) {
            int row = row0 + wrow + (mt << 4) + (quad << 2) + reg;
            if (row >= N) continue;
#pragma unroll
            for (int nt = 0; nt < 4; ++nt) {
                int col = wcol + (nt << 4) + l16;
                float val = acc[mt][nt][reg] + bias[col];
                float cv = sigmoidf_(val);
                size_t o = ((size_t)row << 7) + col;
                float uu = uin[o];
                float hh = hfull[o];
                float hn = uu * hh + (1.0f - uu) * cv;
                outf[o] = hn;
                if (outf2) outf2[o] = hn;
                outb[((size_t)row << obsh) + col] = f2bf(hn);  // next layer's x
            }
        }
    }
}

// ---------------------------------------------------------------------------
extern "C" void kernel_launch(void* const* d_in, const int* in_sizes, int n_in,
                              void* d_out, int out_size, void* d_ws, size_t ws_size,
                              hipStream_t stream) {
    const float* x      = (const float*)d_in[0];
    const float* hidden = (const float*)d_in[1];
    const int*   src    = (const int*)d_in[2];
    const int*   dst    = (const int*)d_in[3];
    const float* ew     = (const float*)d_in[4];
    const float* Wself  = (const float*)d_in[5];
    const float* Wneigh = (const float*)d_in[6];
    const float* bias   = (const float*)d_in[7];
    float* out = (float*)d_out;

    int N = in_sizes[0] / F;  // 50000
    int E = in_sizes[2];      // 800000
    size_t NF = (size_t)N * F;

    char* p = (char*)d_ws;
    auto alloc = [&](size_t bytes) { char* r = p; p += (bytes + 255) & ~255ull; return r; };
    unsigned short* xh0    = (unsigned short*)alloc(2 * NF * 2);  // [N][256] x|h layer0
    unsigned short* xh1    = (unsigned short*)alloc(2 * NF * 2);  // [N][256] x|h layer1
    unsigned short* agg_xb = (unsigned short*)alloc(NF * 2);
    unsigned short* rhb    = (unsigned short*)alloc(NF * 2);
    float*          u      = (float*)alloc(NF * 4);
    unsigned short* W1b    = (unsigned short*)alloc(2 * 64 * 256 * 8 * 2);
    unsigned short* W2b    = (unsigned short*)alloc(2 * 64 * 128 * 8 * 2);
    int2*           es     = (int2*)alloc((size_t)E * 8);
    int*            cnt    = (int*)alloc((size_t)N * 4);
    int*            offs   = (int*)alloc(((size_t)N + 1) * 4);
    int*            cursor = (int*)alloc((size_t)N * 4);
    int*            bsum   = (int*)alloc(1024 * 4);

    pack_w_bf16<<<dim3(1536), dim3(256), 0, stream>>>(Wself, Wneigh, W1b, W2b);
    int n4 = (int)(NF / 4);
    cvt_all<<<dim3((3 * n4 + 255) / 256), dim3(256), 0, stream>>>(x, hidden, xh0, xh1, n4, NF);

    hipMemsetAsync(cnt, 0, (size_t)N * sizeof(int), stream);
    int eBlocks = (E + 255) / 256;
    hist_dst<<<dim3(eBlocks), dim3(256), 0, stream>>>(dst, cnt, E);
    int nb = (N + 1023) / 1024;  // 49 (<= 1024)
    scan_blk<<<dim3(nb), dim3(1024), 0, stream>>>(cnt, offs, bsum, N);
    scan_tops<<<dim3(1), dim3(1024), 0, stream>>>(bsum, nb, offs + N);
    scan_add<<<dim3(nb), dim3(1024), 0, stream>>>(bsum, offs, cursor, N);
    scatter_edges<<<dim3(eBlocks), dim3(256), 0, stream>>>(src, dst, ew, cursor, es, E);

    float* out_x  = out;
    float* out_h1 = out + NF;
    float* out_h2 = out + 2 * NF;

    int mBlocks = (N + 63) / 64;
    for (int l = 0; l < NLAYERS; ++l) {
        unsigned short* xhL = (l == 0) ? xh0 : xh1;
        const float* hL = hidden + (size_t)l * NF;
        const float* biasL = bias + (size_t)l * 384;

        fused_ru<<<dim3(mBlocks), dim3(256), 0, stream>>>(
            xhL, es, offs, W1b + (size_t)l * 64 * 256 * 8, biasL, hL,
            agg_xb, rhb, u, N);

        float* o1 = (l == 0) ? out_h1 : out_h2;
        float* o2 = (l == NLAYERS - 1) ? out_x : nullptr;
        // l==0: outb -> xh1 cols 0:128 (stride 256, obsh=8) = next layer's x.
        // l==1: outb dead; reuse agg_xb (each block overwrites only its own
        //       rows, after its last staged read of them) with obsh=7.
        unsigned short* obN = (l == 0) ? xh1 : agg_xb;
        int obsh = (l == 0) ? 8 : 7;
        fused_c<<<dim3(mBlocks), dim3(256), 0, stream>>>(
            xhL, rhb, agg_xb, es, offs,
            W2b + (size_t)l * 64 * 128 * 8, biasL + 256, hL, u,
            obN, o1, o2, obsh, N);
    }
}

// Round 5
// 633.589 us; speedup vs baseline: 1.1287x; 1.1287x over previous
//
#include <hip/hip_runtime.h>
#include <math.h>

#define F 128
#define NLAYERS 2

typedef __attribute__((ext_vector_type(8))) short bf16x8s;
typedef __attribute__((ext_vector_type(8))) unsigned short u16x8;
typedef __attribute__((ext_vector_type(4))) float f32x4;

__device__ __forceinline__ float sigmoidf_(float x) { return 1.0f / (1.0f + expf(-x)); }

__device__ __forceinline__ unsigned short f2bf(float f) {
    unsigned int u = __float_as_uint(f);
    u += 0x7fffu + ((u >> 16) & 1u);  // RNE
    return (unsigned short)(u >> 16);
}
__device__ __forceinline__ float bf2f(unsigned short s) {
    return __uint_as_float(((unsigned int)s) << 16);
}

// ---------------------------------------------------------------------------
// Weight pack: f32 [L][3][256][128] -> bf16 k-octet layout.
//  W1b [L][64][256][8]: gates (r|u) as 256 cols, K=512 parts (x,h,agg_x,agg_h)
//  W2b [L][64][128][8]: gate c, K parts (x, rh, agg_x, agg_rh)
// ---------------------------------------------------------------------------
__global__ void pack_w_bf16(const float* __restrict__ Ws, const float* __restrict__ Wn,
                            unsigned short* __restrict__ W1b, unsigned short* __restrict__ W2b) {
    int t = blockIdx.x * blockDim.x + threadIdx.x;
    const int n1 = 2 * 64 * 256 * 8;  // 262144
    if (t < n1) {
        int j = t & 7, n = (t >> 3) & 255, ko = (t >> 11) & 63, l = t >> 17;
        int k = ko * 8 + j;
        int p = k >> 7, r = k & 127, g = n >> 7, c = n & 127;
        const float* W = (p < 2) ? Ws : Wn;
        W1b[t] = f2bf(W[(((l * 3 + g) * 256) + ((p & 1) * 128 + r)) * 128 + c]);
    } else {
        int t2 = t - n1;
        if (t2 >= 2 * 64 * 128 * 8) return;
        int j = t2 & 7, n = (t2 >> 3) & 127, ko = (t2 >> 10) & 63, l = t2 >> 16;
        int k = ko * 8 + j;
        int p = k >> 7, r = k & 127;
        const float* W = (p < 2) ? Ws : Wn;
        W2b[t2] = f2bf(W[(((l * 3 + 2) * 256) + ((p & 1) * 128 + r)) * 128 + n]);
    }
}

// Fused f32 -> bf16 interleave: x -> xh0[:,0:128], h0 -> xh0[:,128:256],
// h1 -> xh1[:,128:256]. Each t handles 4 floats.
__global__ void cvt_all(const float* __restrict__ x, const float* __restrict__ hidden,
                        unsigned short* __restrict__ xh0, unsigned short* __restrict__ xh1,
                        int n4, size_t NF) {
    int t = blockIdx.x * blockDim.x + threadIdx.x;
    const float* in;
    unsigned short* out;
    int tt;
    if (t < n4) { in = x; out = xh0; tt = t; }
    else if (t < 2 * n4) { in = hidden; out = xh0 + 128; tt = t - n4; }
    else if (t < 3 * n4) { in = hidden + NF; out = xh1 + 128; tt = t - 2 * n4; }
    else return;
    float4 v = reinterpret_cast<const float4*>(in)[tt];
    ushort4 o;
    o.x = f2bf(v.x); o.y = f2bf(v.y); o.z = f2bf(v.z); o.w = f2bf(v.w);
    *reinterpret_cast<ushort4*>(out + (((size_t)(tt >> 5)) << 8) + ((tt & 31) << 2)) = o;
}

// ---------------------------------------------------------------------------
// CSR build with composite key = dst*16 + (src>>12): per-dst edge lists come
// out bucketed by src range (13 live buckets of 4096 rows) -> all blocks walk
// the table front-to-back in loose lockstep -> L2-resident working set.
// ---------------------------------------------------------------------------
__global__ void hist_key(const int* __restrict__ src, const int* __restrict__ dst,
                         int* __restrict__ cnt, int E) {
    int e = blockIdx.x * blockDim.x + threadIdx.x;
    if (e < E) atomicAdd(&cnt[(dst[e] << 4) + (src[e] >> 12)], 1);
}

__global__ __launch_bounds__(1024) void scan_blk(const int* __restrict__ cnt,
                                                 int* __restrict__ offs,
                                                 int* __restrict__ bsum, int n) {
    __shared__ int wsum[16];
    int tid = threadIdx.x, lane = tid & 63, wid = tid >> 6;
    int i = blockIdx.x * 1024 + tid;
    int v = (i < n) ? cnt[i] : 0;
    int incl = v;
#pragma unroll
    for (int off = 1; off < 64; off <<= 1) {
        int t = __shfl_up(incl, off, 64);
        if (lane >= off) incl += t;
    }
    if (lane == 63) wsum[wid] = incl;
    __syncthreads();
    if (wid == 0) {
        int s = (lane < 16) ? wsum[lane] : 0;
#pragma unroll
        for (int off = 1; off < 16; off <<= 1) {
            int t = __shfl_up(s, off, 64);
            if (lane >= off) s += t;
        }
        if (lane < 16) wsum[lane] = s;
    }
    __syncthreads();
    int wbase = (wid > 0) ? wsum[wid - 1] : 0;
    if (i < n) offs[i] = wbase + incl - v;
    if (tid == 1023) bsum[blockIdx.x] = wbase + incl;
}

__global__ __launch_bounds__(1024) void scan_tops(int* __restrict__ bsum, int nb,
                                                  int* __restrict__ total_out) {
    __shared__ int wsum[16];
    int tid = threadIdx.x, lane = tid & 63, wid = tid >> 6;
    int v = (tid < nb) ? bsum[tid] : 0;
    int incl = v;
#pragma unroll
    for (int off = 1; off < 64; off <<= 1) {
        int t = __shfl_up(incl, off, 64);
        if (lane >= off) incl += t;
    }
    if (lane == 63) wsum[wid] = incl;
    __syncthreads();
    if (wid == 0) {
        int s = (lane < 16) ? wsum[lane] : 0;
#pragma unroll
        for (int off = 1; off < 16; off <<= 1) {
            int t = __shfl_up(s, off, 64);
            if (lane >= off) s += t;
        }
        if (lane < 16) wsum[lane] = s;
    }
    __syncthreads();
    int wbase = (wid > 0) ? wsum[wid - 1] : 0;
    if (tid < nb) bsum[tid] = wbase + incl - v;
    if (tid == 1023) *total_out = wbase + incl;
}

__global__ __launch_bounds__(1024) void scan_add(const int* __restrict__ bsum,
                                                 int* __restrict__ offs,
                                                 int* __restrict__ cursor, int n) {
    int i = blockIdx.x * 1024 + threadIdx.x;
    if (i >= n) return;
    int o = offs[i] + bsum[blockIdx.x];
    offs[i] = o;
    cursor[i] = o;
}

__global__ void scatter_edges(const int* __restrict__ src, const int* __restrict__ dst,
                              const float* __restrict__ ew, int* __restrict__ cursor,
                              int2* __restrict__ es, int E) {
    int e = blockIdx.x * blockDim.x + threadIdx.x;
    if (e >= E) return;
    int s = src[e];
    int key = (dst[e] << 4) + (s >> 12);
    int p = atomicAdd(&cursor[key], 1);
    es[p] = make_int2(s, __float_as_int(ew[e]));
}

// ---------------------------------------------------------------------------
// CSR aggregation over interleaved xh[N][256] bf16: 32 lanes/node, each lane
// one 16B (ushort8) gather per edge. Node segment = offs2[n*16 .. n*16+16).
// ---------------------------------------------------------------------------
__global__ __launch_bounds__(256) void agg_csr2_i(
    const unsigned short* __restrict__ XH,
    const int2* __restrict__ es, const int* __restrict__ offs2,
    unsigned short* __restrict__ agg0, unsigned short* __restrict__ agg1, int N) {
    int node = blockIdx.x * 8 + (threadIdx.x >> 5);
    if (node >= N) return;
    int lane = threadIdx.x & 31;
    int beg = offs2[node << 4], end = offs2[(node << 4) + 16];
    float a0[8] = {0, 0, 0, 0, 0, 0, 0, 0};
    float a1[8] = {0, 0, 0, 0, 0, 0, 0, 0};
    int loff = lane << 3;
    int i = beg;
    for (; i + 3 < end; i += 4) {
        int2 e0 = es[i], e1 = es[i + 1], e2 = es[i + 2], e3 = es[i + 3];
        u16x8 v0 = *reinterpret_cast<const u16x8*>(XH + (((size_t)e0.x) << 8) + loff);
        u16x8 v1 = *reinterpret_cast<const u16x8*>(XH + (((size_t)e1.x) << 8) + loff);
        u16x8 v2 = *reinterpret_cast<const u16x8*>(XH + (((size_t)e2.x) << 8) + loff);
        u16x8 v3 = *reinterpret_cast<const u16x8*>(XH + (((size_t)e3.x) << 8) + loff);
        float w0 = __int_as_float(e0.y), w1 = __int_as_float(e1.y);
        float w2 = __int_as_float(e2.y), w3 = __int_as_float(e3.y);
#pragma unroll
        for (int j = 0; j < 8; ++j) {
            a0[j] += w0 * bf2f(v0[j]);
            a1[j] += w1 * bf2f(v1[j]);
            a0[j] += w2 * bf2f(v2[j]);
            a1[j] += w3 * bf2f(v3[j]);
        }
    }
    for (; i < end; ++i) {
        int2 e0 = es[i];
        float w0 = __int_as_float(e0.y);
        u16x8 v0 = *reinterpret_cast<const u16x8*>(XH + (((size_t)e0.x) << 8) + loff);
#pragma unroll
        for (int j = 0; j < 8; ++j) a0[j] += w0 * bf2f(v0[j]);
    }
    u16x8 o;
#pragma unroll
    for (int j = 0; j < 8; ++j) o[j] = f2bf(a0[j] + a1[j]);
    unsigned short* op = (lane < 16)
        ? (agg0 + (((size_t)node) << 7) + (lane << 3))
        : (agg1 + (((size_t)node) << 7) + ((lane & 15) << 3));
    *reinterpret_cast<u16x8*>(op) = o;
}

// Single-table CSR aggregation (rh, [N][128] bf16): 32 lanes x 8B, unroll-4.
__global__ __launch_bounds__(256) void agg_csr1_b(
    const unsigned short* __restrict__ V0,
    const int2* __restrict__ es, const int* __restrict__ offs2,
    unsigned short* __restrict__ agg0, int N) {
    int node = blockIdx.x * 8 + (threadIdx.x >> 5);
    if (node >= N) return;
    int lane = threadIdx.x & 31;
    int beg = offs2[node << 4], end = offs2[(node << 4) + 16];
    float p0[4] = {0, 0, 0, 0}, p1[4] = {0, 0, 0, 0};
    int loff = lane << 2;
    int i = beg;
    for (; i + 3 < end; i += 4) {
        int2 e0 = es[i], e1 = es[i + 1], e2 = es[i + 2], e3 = es[i + 3];
        ushort4 x0 = *reinterpret_cast<const ushort4*>(V0 + (((size_t)e0.x) << 7) + loff);
        ushort4 x1 = *reinterpret_cast<const ushort4*>(V0 + (((size_t)e1.x) << 7) + loff);
        ushort4 x2 = *reinterpret_cast<const ushort4*>(V0 + (((size_t)e2.x) << 7) + loff);
        ushort4 x3 = *reinterpret_cast<const ushort4*>(V0 + (((size_t)e3.x) << 7) + loff);
        float w0 = __int_as_float(e0.y), w1 = __int_as_float(e1.y);
        float w2 = __int_as_float(e2.y), w3 = __int_as_float(e3.y);
        p0[0] += w0 * bf2f(x0.x); p0[1] += w0 * bf2f(x0.y);
        p0[2] += w0 * bf2f(x0.z); p0[3] += w0 * bf2f(x0.w);
        p1[0] += w1 * bf2f(x1.x); p1[1] += w1 * bf2f(x1.y);
        p1[2] += w1 * bf2f(x1.z); p1[3] += w1 * bf2f(x1.w);
        p0[0] += w2 * bf2f(x2.x); p0[1] += w2 * bf2f(x2.y);
        p0[2] += w2 * bf2f(x2.z); p0[3] += w2 * bf2f(x2.w);
        p1[0] += w3 * bf2f(x3.x); p1[1] += w3 * bf2f(x3.y);
        p1[2] += w3 * bf2f(x3.z); p1[3] += w3 * bf2f(x3.w);
    }
    for (; i < end; ++i) {
        int2 e0 = es[i];
        float w0 = __int_as_float(e0.y);
        ushort4 x0 = *reinterpret_cast<const ushort4*>(V0 + (((size_t)e0.x) << 7) + loff);
        p0[0] += w0 * bf2f(x0.x); p0[1] += w0 * bf2f(x0.y);
        p0[2] += w0 * bf2f(x0.z); p0[3] += w0 * bf2f(x0.w);
    }
    size_t ob = (((size_t)node) << 7) + loff;
    ushort4 o0;
    o0.x = f2bf(p0[0] + p1[0]); o0.y = f2bf(p0[1] + p1[1]);
    o0.z = f2bf(p0[2] + p1[2]); o0.w = f2bf(p0[3] + p1[3]);
    *reinterpret_cast<ushort4*>(agg0 + ob) = o0;
}

// ---------------------------------------------------------------------------
// GEMM gates r|u: 64x256 tile (full N in one block), K=512, 4 waves (2x2),
// 2x8 frags/wave, double-buffered LDS. A parts: x,h from xh (stride 256),
// aggx/aggh (stride 128). B = W1b k-octet layout.
// Epilogue: col<128 -> rhb = bf16(sigmoid*h); col>=128 -> u = sigmoid (f32)
// LDS: Als 8KB + Bls 32KB = 40KB -> 4 blocks/CU.
// ---------------------------------------------------------------------------
__global__ __launch_bounds__(256) void gemm_ru(
    const unsigned short* __restrict__ XH,
    const unsigned short* __restrict__ AGGX, const unsigned short* __restrict__ AGGH,
    const unsigned short* __restrict__ Wb, const float* __restrict__ bias,
    const float* __restrict__ hfull,
    unsigned short* __restrict__ rhb, float* __restrict__ u, int N) {
    __shared__ __align__(16) unsigned short Als[2][4 * 64 * 8];   // 8KB
    __shared__ __align__(16) unsigned short Bls[2][4 * 256 * 8];  // 32KB

    int tid = threadIdx.x;
    int row0 = blockIdx.x * 64;
    int lane = tid & 63;
    int w = tid >> 6;
    int wrow = (w & 1) << 5;       // 0 / 32
    int wcol = (w >> 1) << 7;      // 0 / 128
    int quad = lane >> 4, l16 = lane & 15;

    f32x4 acc[2][8];
    const f32x4 z4 = {0.f, 0.f, 0.f, 0.f};
#pragma unroll
    for (int mt = 0; mt < 2; ++mt)
#pragma unroll
        for (int nt = 0; nt < 8; ++nt) acc[mt][nt] = z4;

    int growA = row0 + lane;
    if (growA >= N) growA = N - 1;

    auto stage = [&](int ks, int buf) {
        int p = ks >> 7;
        const unsigned short* ga =
            (p == 0) ? (XH + (size_t)growA * 256 + (ks & 127) + (w << 3))
          : (p == 1) ? (XH + (size_t)growA * 256 + 128 + (ks & 127) + (w << 3))
          : (p == 2) ? (AGGX + ((size_t)growA << 7) + (ks & 127) + (w << 3))
                     : (AGGH + ((size_t)growA << 7) + (ks & 127) + (w << 3));
        __builtin_amdgcn_global_load_lds(
            (const __attribute__((address_space(1))) void*)ga,
            (__attribute__((address_space(3))) void*)&Als[buf][((w << 6) + lane) << 3], 16, 0, 0);
#pragma unroll
        for (int r = 0; r < 4; ++r) {
            int q = r, n = tid;  // 256 threads: one col each, 4 q rounds
            int koG = (ks >> 3) + q;
            const unsigned short* gb = Wb + ((size_t)(koG * 256 + n) << 3);
            __builtin_amdgcn_global_load_lds(
                (const __attribute__((address_space(1))) void*)gb,
                (__attribute__((address_space(3))) void*)&Bls[buf][((q << 8) + n) << 3], 16, 0, 0);
        }
    };

    stage(0, 0);
    __syncthreads();
    int buf = 0;
    for (int ks = 0; ks < 512; ks += 32, buf ^= 1) {
        if (ks + 32 < 512) stage(ks + 32, buf ^ 1);

        bf16x8s af[2], bfr[8];
#pragma unroll
        for (int mt = 0; mt < 2; ++mt)
            af[mt] = *reinterpret_cast<const bf16x8s*>(
                &Als[buf][((quad << 6) + wrow + (mt << 4) + l16) << 3]);
#pragma unroll
        for (int nt = 0; nt < 8; ++nt)
            bfr[nt] = *reinterpret_cast<const bf16x8s*>(
                &Bls[buf][((quad << 8) + wcol + (nt << 4) + l16) << 3]);
#pragma unroll
        for (int mt = 0; mt < 2; ++mt)
#pragma unroll
            for (int nt = 0; nt < 8; ++nt)
                acc[mt][nt] = __builtin_amdgcn_mfma_f32_16x16x32_bf16(
                    af[mt], bfr[nt], acc[mt][nt], 0, 0, 0);
        __syncthreads();
    }

#pragma unroll
    for (int mt = 0; mt < 2; ++mt) {
#pragma unroll
        for (int reg = 0; reg < 4; ++reg) {
            int row = row0 + wrow + (mt << 4) + (quad << 2) + reg;
            if (row >= N) continue;
#pragma unroll
            for (int nt = 0; nt < 8; ++nt) {
                int col = wcol + (nt << 4) + l16;
                float val = acc[mt][nt][reg] + bias[col];
                float sg = sigmoidf_(val);
                int c = col & 127;
                size_t o = ((size_t)row << 7) + c;
                if (col < 128)
                    rhb[o] = f2bf(sg * hfull[o]);   // rh = r*h (bf16)
                else
                    u[o] = sg;                       // u (f32)
            }
        }
    }
}

// ---------------------------------------------------------------------------
// GEMM gate c: 64x128 tile, K=512, as round-2 verified. A parts:
// x (xh stride 256), rh (128), aggx (128), agg_rh (128). B = W2b.
// Epilogue: c = sigmoid; hn = u*h+(1-u)*c -> outf (+outf2); outb = bf16(hn)
// with row shift obsh (8 -> next xh cols 0:128, 7 -> plain 128-col table).
// ---------------------------------------------------------------------------
__global__ __launch_bounds__(256) void gemm_c(
    const unsigned short* __restrict__ XH, const unsigned short* __restrict__ RHB,
    const unsigned short* __restrict__ AGGX, const unsigned short* __restrict__ AGGR,
    const unsigned short* __restrict__ Wb, const float* __restrict__ bias,
    const float* __restrict__ hfull, const float* __restrict__ uin,
    unsigned short* __restrict__ outb, float* __restrict__ outf,
    float* __restrict__ outf2, int obsh, int N) {
    __shared__ __align__(16) unsigned short Als[2][4 * 64 * 8];   // 8KB
    __shared__ __align__(16) unsigned short Bls[2][4 * 128 * 8];  // 16KB

    int tid = threadIdx.x;
    int row0 = blockIdx.x * 64;
    int lane = tid & 63;
    int w = tid >> 6;
    int wrow = (w & 1) << 5;
    int wcol = (w >> 1) << 6;
    int quad = lane >> 4, l16 = lane & 15;

    f32x4 acc[2][4];
    const f32x4 z4 = {0.f, 0.f, 0.f, 0.f};
#pragma unroll
    for (int mt = 0; mt < 2; ++mt)
#pragma unroll
        for (int nt = 0; nt < 4; ++nt) acc[mt][nt] = z4;

    int growA = row0 + lane;
    if (growA >= N) growA = N - 1;
    int qB = tid >> 7, nB = tid & 127;

    auto stage = [&](int ks, int buf) {
        int p = ks >> 7;
        const unsigned short* ga =
            (p == 0) ? (XH + (size_t)growA * 256 + (ks & 127) + (w << 3))
          : (p == 1) ? (RHB + ((size_t)growA << 7) + (ks & 127) + (w << 3))
          : (p == 2) ? (AGGX + ((size_t)growA << 7) + (ks & 127) + (w << 3))
                     : (AGGR + ((size_t)growA << 7) + (ks & 127) + (w << 3));
        __builtin_amdgcn_global_load_lds(
            (const __attribute__((address_space(1))) void*)ga,
            (__attribute__((address_space(3))) void*)&Als[buf][((w << 6) + lane) << 3], 16, 0, 0);
#pragma unroll
        for (int r = 0; r < 2; ++r) {
            int q = 2 * r + qB;
            int koG = (ks >> 3) + q;
            const unsigned short* gb = Wb + ((size_t)(koG * 128 + nB) << 3);
            __builtin_amdgcn_global_load_lds(
                (const __attribute__((address_space(1))) void*)gb,
                (__attribute__((address_space(3))) void*)&Bls[buf][((q << 7) + nB) << 3], 16, 0, 0);
        }
    };

    stage(0, 0);
    __syncthreads();
    int buf = 0;
    for (int ks = 0; ks < 512; ks += 32, buf ^= 1) {
        if (ks + 32 < 512) stage(ks + 32, buf ^ 1);

        bf16x8s af[2], bfr[4];
#pragma unroll
        for (int mt = 0; mt < 2; ++mt)
            af[mt] = *reinterpret_cast<const bf16x8s*>(
                &Als[buf][((quad << 6) + wrow + (mt << 4) + l16) << 3]);
#pragma unroll
        for (int nt = 0; nt < 4; ++nt)
            bfr[nt] = *reinterpret_cast<const bf16x8s*>(
                &Bls[buf][((quad << 7) + wcol + (nt << 4) + l16) << 3]);
#pragma unroll
        for (int mt = 0; mt < 2; ++mt)
#pragma unroll
            for (int nt = 0; nt < 4; ++nt)
                acc[mt][nt] = __builtin_amdgcn_mfma_f32_16x16x32_bf16(
                    af[mt], bfr[nt], acc[mt][nt], 0, 0, 0);
        __syncthreads();
    }

#pragma unroll
    for (int mt = 0; mt < 2; ++mt) {
#pragma unroll
        for (int reg = 0; reg < 4; ++reg) {
            int row = row0 + wrow + (mt << 4) + (quad << 2) + reg;
            if (row >= N) continue;
#pragma unroll
            for (int nt = 0; nt < 4; ++nt) {
                int col = wcol + (nt << 4) + l16;
                float val = acc[mt][nt][reg] + bias[col];
                float cv = sigmoidf_(val);
                size_t o = ((size_t)row << 7) + col;
                float uu = uin[o];
                float hh = hfull[o];
                float hn = uu * hh + (1.0f - uu) * cv;
                outf[o] = hn;
                if (outf2) outf2[o] = hn;
                outb[((size_t)row << obsh) + col] = f2bf(hn);  // next layer's x
            }
        }
    }
}

// ---------------------------------------------------------------------------
extern "C" void kernel_launch(void* const* d_in, const int* in_sizes, int n_in,
                              void* d_out, int out_size, void* d_ws, size_t ws_size,
                              hipStream_t stream) {
    const float* x      = (const float*)d_in[0];
    const float* hidden = (const float*)d_in[1];
    const int*   src    = (const int*)d_in[2];
    const int*   dst    = (const int*)d_in[3];
    const float* ew     = (const float*)d_in[4];
    const float* Wself  = (const float*)d_in[5];
    const float* Wneigh = (const float*)d_in[6];
    const float* bias   = (const float*)d_in[7];
    float* out = (float*)d_out;

    int N = in_sizes[0] / F;  // 50000
    int E = in_sizes[2];      // 800000
    size_t NF = (size_t)N * F;
    int NK = N * 16;          // composite key space: dst*16 + src-bucket

    char* p = (char*)d_ws;
    auto alloc = [&](size_t bytes) { char* r = p; p += (bytes + 255) & ~255ull; return r; };
    unsigned short* xh0    = (unsigned short*)alloc(2 * NF * 2);  // [N][256] x|h layer0
    unsigned short* xh1    = (unsigned short*)alloc(2 * NF * 2);  // [N][256] x|h layer1
    unsigned short* agg_xb = (unsigned short*)alloc(NF * 2);
    unsigned short* agg_hb = (unsigned short*)alloc(NF * 2);
    unsigned short* agg_rb = (unsigned short*)alloc(NF * 2);
    unsigned short* rhb    = (unsigned short*)alloc(NF * 2);
    float*          u      = (float*)alloc(NF * 4);
    unsigned short* W1b    = (unsigned short*)alloc(2 * 64 * 256 * 8 * 2);
    unsigned short* W2b    = (unsigned short*)alloc(2 * 64 * 128 * 8 * 2);
    int2*           es     = (int2*)alloc((size_t)E * 8);
    int*            cnt2   = (int*)alloc((size_t)NK * 4);
    int*            offs2  = (int*)alloc(((size_t)NK + 1) * 4);
    int*            cur2   = (int*)alloc((size_t)NK * 4);
    int*            bsum   = (int*)alloc(1024 * 4);

    pack_w_bf16<<<dim3(1536), dim3(256), 0, stream>>>(Wself, Wneigh, W1b, W2b);
    int n4 = (int)(NF / 4);
    cvt_all<<<dim3((3 * n4 + 255) / 256), dim3(256), 0, stream>>>(x, hidden, xh0, xh1, n4, NF);

    hipMemsetAsync(cnt2, 0, (size_t)NK * sizeof(int), stream);
    int eBlocks = (E + 255) / 256;
    hist_key<<<dim3(eBlocks), dim3(256), 0, stream>>>(src, dst, cnt2, E);
    int nb = (NK + 1023) / 1024;  // 782 (<= 1024)
    scan_blk<<<dim3(nb), dim3(1024), 0, stream>>>(cnt2, offs2, bsum, NK);
    scan_tops<<<dim3(1), dim3(1024), 0, stream>>>(bsum, nb, offs2 + NK);
    scan_add<<<dim3(nb), dim3(1024), 0, stream>>>(bsum, offs2, cur2, NK);
    scatter_edges<<<dim3(eBlocks), dim3(256), 0, stream>>>(src, dst, ew, cur2, es, E);

    float* out_x  = out;
    float* out_h1 = out + NF;
    float* out_h2 = out + 2 * NF;

    int aggBlocks = (N + 7) / 8;
    int mBlocks = (N + 63) / 64;
    for (int l = 0; l < NLAYERS; ++l) {
        unsigned short* xhL = (l == 0) ? xh0 : xh1;
        const float* hL = hidden + (size_t)l * NF;
        const float* biasL = bias + (size_t)l * 384;

        agg_csr2_i<<<dim3(aggBlocks), dim3(256), 0, stream>>>(xhL, es, offs2,
                                                              agg_xb, agg_hb, N);

        gemm_ru<<<dim3(mBlocks), dim3(256), 0, stream>>>(
            xhL, agg_xb, agg_hb,
            W1b + (size_t)l * 64 * 256 * 8, biasL, hL,
            rhb, u, N);

        agg_csr1_b<<<dim3(aggBlocks), dim3(256), 0, stream>>>(rhb, es, offs2, agg_rb, N);

        float* o1 = (l == 0) ? out_h1 : out_h2;
        float* o2 = (l == NLAYERS - 1) ? out_x : nullptr;
        // l==0: outb -> xh1 cols 0:128 (stride 256, obsh=8) = next layer's x.
        // l==1: outb dead; reuse agg_rb (each block writes only its own rows,
        //       after its last staged read of them) with obsh=7.
        unsigned short* obN = (l == 0) ? xh1 : agg_rb;
        int obsh = (l == 0) ? 8 : 7;
        gemm_c<<<dim3(mBlocks), dim3(256), 0, stream>>>(
            xhL, rhb, agg_xb, agg_rb,
            W2b + (size_t)l * 64 * 128 * 8, biasL + 256, hL, u,
            obN, o1, o2, obsh, N);
    }
}

// Round 6
// 589.005 us; speedup vs baseline: 1.2142x; 1.0757x over previous
//
#include <hip/hip_runtime.h>
#include <math.h>

#define F 128
#define NLAYERS 2

typedef __attribute__((ext_vector_type(8))) short bf16x8s;
typedef __attribute__((ext_vector_type(8))) unsigned short u16x8;
typedef __attribute__((ext_vector_type(4))) float f32x4;

__device__ __forceinline__ float sigmoidf_(float x) { return 1.0f / (1.0f + expf(-x)); }

__device__ __forceinline__ unsigned short f2bf(float f) {
    unsigned int u = __float_as_uint(f);
    u += 0x7fffu + ((u >> 16) & 1u);  // RNE
    return (unsigned short)(u >> 16);
}
__device__ __forceinline__ float bf2f(unsigned short s) {
    return __uint_as_float(((unsigned int)s) << 16);
}

// ---------------------------------------------------------------------------
// Weight pack: f32 [L][3][256][128] -> bf16 k-octet layout.
//  W1b [L][64][256][8]: gates (r|u) as 256 cols, K=512 parts (x,h,agg_x,agg_h)
//  W2b [L][64][128][8]: gate c, K parts (x, rh, agg_x, agg_rh)
// ---------------------------------------------------------------------------
__global__ void pack_w_bf16(const float* __restrict__ Ws, const float* __restrict__ Wn,
                            unsigned short* __restrict__ W1b, unsigned short* __restrict__ W2b) {
    int t = blockIdx.x * blockDim.x + threadIdx.x;
    const int n1 = 2 * 64 * 256 * 8;  // 262144
    if (t < n1) {
        int j = t & 7, n = (t >> 3) & 255, ko = (t >> 11) & 63, l = t >> 17;
        int k = ko * 8 + j;
        int p = k >> 7, r = k & 127, g = n >> 7, c = n & 127;
        const float* W = (p < 2) ? Ws : Wn;
        W1b[t] = f2bf(W[(((l * 3 + g) * 256) + ((p & 1) * 128 + r)) * 128 + c]);
    } else {
        int t2 = t - n1;
        if (t2 >= 2 * 64 * 128 * 8) return;
        int j = t2 & 7, n = (t2 >> 3) & 127, ko = (t2 >> 10) & 63, l = t2 >> 16;
        int k = ko * 8 + j;
        int p = k >> 7, r = k & 127;
        const float* W = (p < 2) ? Ws : Wn;
        W2b[t2] = f2bf(W[(((l * 3 + 2) * 256) + ((p & 1) * 128 + r)) * 128 + n]);
    }
}

// Fused f32 -> bf16 interleave: x -> xh0[:,0:128], h0 -> xh0[:,128:256],
// h1 -> xh1[:,128:256]. Each t handles 4 floats.
__global__ void cvt_all(const float* __restrict__ x, const float* __restrict__ hidden,
                        unsigned short* __restrict__ xh0, unsigned short* __restrict__ xh1,
                        int n4, size_t NF) {
    int t = blockIdx.x * blockDim.x + threadIdx.x;
    const float* in;
    unsigned short* out;
    int tt;
    if (t < n4) { in = x; out = xh0; tt = t; }
    else if (t < 2 * n4) { in = hidden; out = xh0 + 128; tt = t - n4; }
    else if (t < 3 * n4) { in = hidden + NF; out = xh1 + 128; tt = t - 2 * n4; }
    else return;
    float4 v = reinterpret_cast<const float4*>(in)[tt];
    ushort4 o;
    o.x = f2bf(v.x); o.y = f2bf(v.y); o.z = f2bf(v.z); o.w = f2bf(v.w);
    *reinterpret_cast<ushort4*>(out + (((size_t)(tt >> 5)) << 8) + ((tt & 31) << 2)) = o;
}

// ---------------------------------------------------------------------------
// CSR build with composite key = dst*16 + (src>>12): per-dst edge lists come
// out bucketed by src range (13 live buckets of 4096 rows) -> all blocks walk
// the table front-to-back in loose lockstep -> L2-resident working set.
// ---------------------------------------------------------------------------
__global__ void hist_key(const int* __restrict__ src, const int* __restrict__ dst,
                         int* __restrict__ cnt, int E) {
    int e = blockIdx.x * blockDim.x + threadIdx.x;
    if (e < E) atomicAdd(&cnt[(dst[e] << 4) + (src[e] >> 12)], 1);
}

__global__ __launch_bounds__(1024) void scan_blk(const int* __restrict__ cnt,
                                                 int* __restrict__ offs,
                                                 int* __restrict__ bsum, int n) {
    __shared__ int wsum[16];
    int tid = threadIdx.x, lane = tid & 63, wid = tid >> 6;
    int i = blockIdx.x * 1024 + tid;
    int v = (i < n) ? cnt[i] : 0;
    int incl = v;
#pragma unroll
    for (int off = 1; off < 64; off <<= 1) {
        int t = __shfl_up(incl, off, 64);
        if (lane >= off) incl += t;
    }
    if (lane == 63) wsum[wid] = incl;
    __syncthreads();
    if (wid == 0) {
        int s = (lane < 16) ? wsum[lane] : 0;
#pragma unroll
        for (int off = 1; off < 16; off <<= 1) {
            int t = __shfl_up(s, off, 64);
            if (lane >= off) s += t;
        }
        if (lane < 16) wsum[lane] = s;
    }
    __syncthreads();
    int wbase = (wid > 0) ? wsum[wid - 1] : 0;
    if (i < n) offs[i] = wbase + incl - v;
    if (tid == 1023) bsum[blockIdx.x] = wbase + incl;
}

__global__ __launch_bounds__(1024) void scan_tops(int* __restrict__ bsum, int nb,
                                                  int* __restrict__ total_out) {
    __shared__ int wsum[16];
    int tid = threadIdx.x, lane = tid & 63, wid = tid >> 6;
    int v = (tid < nb) ? bsum[tid] : 0;
    int incl = v;
#pragma unroll
    for (int off = 1; off < 64; off <<= 1) {
        int t = __shfl_up(incl, off, 64);
        if (lane >= off) incl += t;
    }
    if (lane == 63) wsum[wid] = incl;
    __syncthreads();
    if (wid == 0) {
        int s = (lane < 16) ? wsum[lane] : 0;
#pragma unroll
        for (int off = 1; off < 16; off <<= 1) {
            int t = __shfl_up(s, off, 64);
            if (lane >= off) s += t;
        }
        if (lane < 16) wsum[lane] = s;
    }
    __syncthreads();
    int wbase = (wid > 0) ? wsum[wid - 1] : 0;
    if (tid < nb) bsum[tid] = wbase + incl - v;
    if (tid == 1023) *total_out = wbase + incl;
}

__global__ __launch_bounds__(1024) void scan_add(const int* __restrict__ bsum,
                                                 int* __restrict__ offs,
                                                 int* __restrict__ cursor, int n) {
    int i = blockIdx.x * 1024 + threadIdx.x;
    if (i >= n) return;
    int o = offs[i] + bsum[blockIdx.x];
    offs[i] = o;
    cursor[i] = o;
}

__global__ void scatter_edges(const int* __restrict__ src, const int* __restrict__ dst,
                              const float* __restrict__ ew, int* __restrict__ cursor,
                              int2* __restrict__ es, int E) {
    int e = blockIdx.x * blockDim.x + threadIdx.x;
    if (e >= E) return;
    int s = src[e];
    int key = (dst[e] << 4) + (s >> 12);
    int p = atomicAdd(&cursor[key], 1);
    es[p] = make_int2(s, __float_as_int(ew[e]));
}

// ---------------------------------------------------------------------------
// CSR aggregation over interleaved xh[N][256] bf16: 32 lanes/node, each lane
// one 16B (ushort8) gather per edge. Node segment = offs2[n*16 .. n*16+16).
// ---------------------------------------------------------------------------
__global__ __launch_bounds__(256) void agg_csr2_i(
    const unsigned short* __restrict__ XH,
    const int2* __restrict__ es, const int* __restrict__ offs2,
    unsigned short* __restrict__ agg0, unsigned short* __restrict__ agg1, int N) {
    int node = blockIdx.x * 8 + (threadIdx.x >> 5);
    if (node >= N) return;
    int lane = threadIdx.x & 31;
    int beg = offs2[node << 4], end = offs2[(node << 4) + 16];
    float a0[8] = {0, 0, 0, 0, 0, 0, 0, 0};
    float a1[8] = {0, 0, 0, 0, 0, 0, 0, 0};
    int loff = lane << 3;
    int i = beg;
    for (; i + 3 < end; i += 4) {
        int2 e0 = es[i], e1 = es[i + 1], e2 = es[i + 2], e3 = es[i + 3];
        u16x8 v0 = *reinterpret_cast<const u16x8*>(XH + (((size_t)e0.x) << 8) + loff);
        u16x8 v1 = *reinterpret_cast<const u16x8*>(XH + (((size_t)e1.x) << 8) + loff);
        u16x8 v2 = *reinterpret_cast<const u16x8*>(XH + (((size_t)e2.x) << 8) + loff);
        u16x8 v3 = *reinterpret_cast<const u16x8*>(XH + (((size_t)e3.x) << 8) + loff);
        float w0 = __int_as_float(e0.y), w1 = __int_as_float(e1.y);
        float w2 = __int_as_float(e2.y), w3 = __int_as_float(e3.y);
#pragma unroll
        for (int j = 0; j < 8; ++j) {
            a0[j] += w0 * bf2f(v0[j]);
            a1[j] += w1 * bf2f(v1[j]);
            a0[j] += w2 * bf2f(v2[j]);
            a1[j] += w3 * bf2f(v3[j]);
        }
    }
    for (; i < end; ++i) {
        int2 e0 = es[i];
        float w0 = __int_as_float(e0.y);
        u16x8 v0 = *reinterpret_cast<const u16x8*>(XH + (((size_t)e0.x) << 8) + loff);
#pragma unroll
        for (int j = 0; j < 8; ++j) a0[j] += w0 * bf2f(v0[j]);
    }
    u16x8 o;
#pragma unroll
    for (int j = 0; j < 8; ++j) o[j] = f2bf(a0[j] + a1[j]);
    unsigned short* op = (lane < 16)
        ? (agg0 + (((size_t)node) << 7) + (lane << 3))
        : (agg1 + (((size_t)node) << 7) + ((lane & 15) << 3));
    *reinterpret_cast<u16x8*>(op) = o;
}

// Single-table CSR aggregation (rh, [N][128] bf16): 32 lanes x 8B, unroll-4.
__global__ __launch_bounds__(256) void agg_csr1_b(
    const unsigned short* __restrict__ V0,
    const int2* __restrict__ es, const int* __restrict__ offs2,
    unsigned short* __restrict__ agg0, int N) {
    int node = blockIdx.x * 8 + (threadIdx.x >> 5);
    if (node >= N) return;
    int lane = threadIdx.x & 31;
    int beg = offs2[node << 4], end = offs2[(node << 4) + 16];
    float p0[4] = {0, 0, 0, 0}, p1[4] = {0, 0, 0, 0};
    int loff = lane << 2;
    int i = beg;
    for (; i + 3 < end; i += 4) {
        int2 e0 = es[i], e1 = es[i + 1], e2 = es[i + 2], e3 = es[i + 3];
        ushort4 x0 = *reinterpret_cast<const ushort4*>(V0 + (((size_t)e0.x) << 7) + loff);
        ushort4 x1 = *reinterpret_cast<const ushort4*>(V0 + (((size_t)e1.x) << 7) + loff);
        ushort4 x2 = *reinterpret_cast<const ushort4*>(V0 + (((size_t)e2.x) << 7) + loff);
        ushort4 x3 = *reinterpret_cast<const ushort4*>(V0 + (((size_t)e3.x) << 7) + loff);
        float w0 = __int_as_float(e0.y), w1 = __int_as_float(e1.y);
        float w2 = __int_as_float(e2.y), w3 = __int_as_float(e3.y);
        p0[0] += w0 * bf2f(x0.x); p0[1] += w0 * bf2f(x0.y);
        p0[2] += w0 * bf2f(x0.z); p0[3] += w0 * bf2f(x0.w);
        p1[0] += w1 * bf2f(x1.x); p1[1] += w1 * bf2f(x1.y);
        p1[2] += w1 * bf2f(x1.z); p1[3] += w1 * bf2f(x1.w);
        p0[0] += w2 * bf2f(x2.x); p0[1] += w2 * bf2f(x2.y);
        p0[2] += w2 * bf2f(x2.z); p0[3] += w2 * bf2f(x2.w);
        p1[0] += w3 * bf2f(x3.x); p1[1] += w3 * bf2f(x3.y);
        p1[2] += w3 * bf2f(x3.z); p1[3] += w3 * bf2f(x3.w);
    }
    for (; i < end; ++i) {
        int2 e0 = es[i];
        float w0 = __int_as_float(e0.y);
        ushort4 x0 = *reinterpret_cast<const ushort4*>(V0 + (((size_t)e0.x) << 7) + loff);
        p0[0] += w0 * bf2f(x0.x); p0[1] += w0 * bf2f(x0.y);
        p0[2] += w0 * bf2f(x0.z); p0[3] += w0 * bf2f(x0.w);
    }
    size_t ob = (((size_t)node) << 7) + loff;
    ushort4 o0;
    o0.x = f2bf(p0[0] + p1[0]); o0.y = f2bf(p0[1] + p1[1]);
    o0.z = f2bf(p0[2] + p1[2]); o0.w = f2bf(p0[3] + p1[3]);
    *reinterpret_cast<ushort4*>(agg0 + ob) = o0;
}

// ---------------------------------------------------------------------------
// GEMM gates r|u: 64x128 tile, y-grid=2 over N=256 cols, K=512, 4 waves (2x2),
// 2x4 frags/wave, double-buffered LDS (24KB). A parts: x,h from xh (stride
// 256), aggx/aggh (stride 128). B = W1b k-octet layout.
// Epilogue: col<128 -> rhb = bf16(sigmoid*h); col>=128 -> u = sigmoid (f32)
// ---------------------------------------------------------------------------
__global__ __launch_bounds__(256) void gemm_ru(
    const unsigned short* __restrict__ XH,
    const unsigned short* __restrict__ AGGX, const unsigned short* __restrict__ AGGH,
    const unsigned short* __restrict__ Wb, const float* __restrict__ bias,
    const float* __restrict__ hfull,
    unsigned short* __restrict__ rhb, float* __restrict__ u, int N) {
    __shared__ __align__(16) unsigned short Als[2][4 * 64 * 8];   // 8KB
    __shared__ __align__(16) unsigned short Bls[2][4 * 128 * 8];  // 16KB

    int tid = threadIdx.x;
    int row0 = blockIdx.x * 64;
    int n0c = blockIdx.y * 128;
    int lane = tid & 63;
    int w = tid >> 6;
    int wrow = (w & 1) << 5;       // 0 / 32
    int wcol = (w >> 1) << 6;      // 0 / 64
    int quad = lane >> 4, l16 = lane & 15;

    f32x4 acc[2][4];
    const f32x4 z4 = {0.f, 0.f, 0.f, 0.f};
#pragma unroll
    for (int mt = 0; mt < 2; ++mt)
#pragma unroll
        for (int nt = 0; nt < 4; ++nt) acc[mt][nt] = z4;

    int growA = row0 + lane;
    if (growA >= N) growA = N - 1;
    int qB = tid >> 7, nB = tid & 127;

    auto stage = [&](int ks, int buf) {
        int p = ks >> 7;
        const unsigned short* ga =
            (p == 0) ? (XH + (size_t)growA * 256 + (ks & 127) + (w << 3))
          : (p == 1) ? (XH + (size_t)growA * 256 + 128 + (ks & 127) + (w << 3))
          : (p == 2) ? (AGGX + ((size_t)growA << 7) + (ks & 127) + (w << 3))
                     : (AGGH + ((size_t)growA << 7) + (ks & 127) + (w << 3));
        __builtin_amdgcn_global_load_lds(
            (const __attribute__((address_space(1))) void*)ga,
            (__attribute__((address_space(3))) void*)&Als[buf][((w << 6) + lane) << 3], 16, 0, 0);
#pragma unroll
        for (int r = 0; r < 2; ++r) {
            int q = 2 * r + qB;
            int koG = (ks >> 3) + q;
            const unsigned short* gb = Wb + ((size_t)(koG * 256 + n0c + nB) << 3);
            __builtin_amdgcn_global_load_lds(
                (const __attribute__((address_space(1))) void*)gb,
                (__attribute__((address_space(3))) void*)&Bls[buf][((q << 7) + nB) << 3], 16, 0, 0);
        }
    };

    stage(0, 0);
    __syncthreads();
    int buf = 0;
    for (int ks = 0; ks < 512; ks += 32, buf ^= 1) {
        if (ks + 32 < 512) stage(ks + 32, buf ^ 1);

        bf16x8s af[2], bfr[4];
#pragma unroll
        for (int mt = 0; mt < 2; ++mt)
            af[mt] = *reinterpret_cast<const bf16x8s*>(
                &Als[buf][((quad << 6) + wrow + (mt << 4) + l16) << 3]);
#pragma unroll
        for (int nt = 0; nt < 4; ++nt)
            bfr[nt] = *reinterpret_cast<const bf16x8s*>(
                &Bls[buf][((quad << 7) + wcol + (nt << 4) + l16) << 3]);
#pragma unroll
        for (int mt = 0; mt < 2; ++mt)
#pragma unroll
            for (int nt = 0; nt < 4; ++nt)
                acc[mt][nt] = __builtin_amdgcn_mfma_f32_16x16x32_bf16(
                    af[mt], bfr[nt], acc[mt][nt], 0, 0, 0);
        __syncthreads();
    }

#pragma unroll
    for (int mt = 0; mt < 2; ++mt) {
#pragma unroll
        for (int reg = 0; reg < 4; ++reg) {
            int row = row0 + wrow + (mt << 4) + (quad << 2) + reg;
            if (row >= N) continue;
#pragma unroll
            for (int nt = 0; nt < 4; ++nt) {
                int col = n0c + wcol + (nt << 4) + l16;
                float val = acc[mt][nt][reg] + bias[col];
                float sg = sigmoidf_(val);
                int c = col & 127;
                size_t o = ((size_t)row << 7) + c;
                if (col < 128)
                    rhb[o] = f2bf(sg * hfull[o]);   // rh = r*h (bf16)
                else
                    u[o] = sg;                       // u (f32)
            }
        }
    }
}

// ---------------------------------------------------------------------------
// GEMM gate c: 64x128 tile, K=512. A parts: x (xh stride 256), rh (128),
// aggx (128), agg_rh (128). B = W2b.
// Epilogue: c = sigmoid; hn = u*h+(1-u)*c -> outf (+outf2); outb = bf16(hn)
// with row shift obsh (8 -> next xh cols 0:128, 7 -> plain 128-col table).
// ---------------------------------------------------------------------------
__global__ __launch_bounds__(256) void gemm_c(
    const unsigned short* __restrict__ XH, const unsigned short* __restrict__ RHB,
    const unsigned short* __restrict__ AGGX, const unsigned short* __restrict__ AGGR,
    const unsigned short* __restrict__ Wb, const float* __restrict__ bias,
    const float* __restrict__ hfull, const float* __restrict__ uin,
    unsigned short* __restrict__ outb, float* __restrict__ outf,
    float* __restrict__ outf2, int obsh, int N) {
    __shared__ __align__(16) unsigned short Als[2][4 * 64 * 8];   // 8KB
    __shared__ __align__(16) unsigned short Bls[2][4 * 128 * 8];  // 16KB

    int tid = threadIdx.x;
    int row0 = blockIdx.x * 64;
    int lane = tid & 63;
    int w = tid >> 6;
    int wrow = (w & 1) << 5;
    int wcol = (w >> 1) << 6;
    int quad = lane >> 4, l16 = lane & 15;

    f32x4 acc[2][4];
    const f32x4 z4 = {0.f, 0.f, 0.f, 0.f};
#pragma unroll
    for (int mt = 0; mt < 2; ++mt)
#pragma unroll
        for (int nt = 0; nt < 4; ++nt) acc[mt][nt] = z4;

    int growA = row0 + lane;
    if (growA >= N) growA = N - 1;
    int qB = tid >> 7, nB = tid & 127;

    auto stage = [&](int ks, int buf) {
        int p = ks >> 7;
        const unsigned short* ga =
            (p == 0) ? (XH + (size_t)growA * 256 + (ks & 127) + (w << 3))
          : (p == 1) ? (RHB + ((size_t)growA << 7) + (ks & 127) + (w << 3))
          : (p == 2) ? (AGGX + ((size_t)growA << 7) + (ks & 127) + (w << 3))
                     : (AGGR + ((size_t)growA << 7) + (ks & 127) + (w << 3));
        __builtin_amdgcn_global_load_lds(
            (const __attribute__((address_space(1))) void*)ga,
            (__attribute__((address_space(3))) void*)&Als[buf][((w << 6) + lane) << 3], 16, 0, 0);
#pragma unroll
        for (int r = 0; r < 2; ++r) {
            int q = 2 * r + qB;
            int koG = (ks >> 3) + q;
            const unsigned short* gb = Wb + ((size_t)(koG * 128 + nB) << 3);
            __builtin_amdgcn_global_load_lds(
                (const __attribute__((address_space(1))) void*)gb,
                (__attribute__((address_space(3))) void*)&Bls[buf][((q << 7) + nB) << 3], 16, 0, 0);
        }
    };

    stage(0, 0);
    __syncthreads();
    int buf = 0;
    for (int ks = 0; ks < 512; ks += 32, buf ^= 1) {
        if (ks + 32 < 512) stage(ks + 32, buf ^ 1);

        bf16x8s af[2], bfr[4];
#pragma unroll
        for (int mt = 0; mt < 2; ++mt)
            af[mt] = *reinterpret_cast<const bf16x8s*>(
                &Als[buf][((quad << 6) + wrow + (mt << 4) + l16) << 3]);
#pragma unroll
        for (int nt = 0; nt < 4; ++nt)
            bfr[nt] = *reinterpret_cast<const bf16x8s*>(
                &Bls[buf][((quad << 7) + wcol + (nt << 4) + l16) << 3]);
#pragma unroll
        for (int mt = 0; mt < 2; ++mt)
#pragma unroll
            for (int nt = 0; nt < 4; ++nt)
                acc[mt][nt] = __builtin_amdgcn_mfma_f32_16x16x32_bf16(
                    af[mt], bfr[nt], acc[mt][nt], 0, 0, 0);
        __syncthreads();
    }

#pragma unroll
    for (int mt = 0; mt < 2; ++mt) {
#pragma unroll
        for (int reg = 0; reg < 4; ++reg) {
            int row = row0 + wrow + (mt << 4) + (quad << 2) + reg;
            if (row >= N) continue;
#pragma unroll
            for (int nt = 0; nt < 4; ++nt) {
                int col = wcol + (nt << 4) + l16;
                float val = acc[mt][nt][reg] + bias[col];
                float cv = sigmoidf_(val);
                size_t o = ((size_t)row << 7) + col;
                float uu = uin[o];
                float hh = hfull[o];
                float hn = uu * hh + (1.0f - uu) * cv;
                outf[o] = hn;
                if (outf2) outf2[o] = hn;
                outb[((size_t)row << obsh) + col] = f2bf(hn);  // next layer's x
            }
        }
    }
}

// ---------------------------------------------------------------------------
extern "C" void kernel_launch(void* const* d_in, const int* in_sizes, int n_in,
                              void* d_out, int out_size, void* d_ws, size_t ws_size,
                              hipStream_t stream) {
    const float* x      = (const float*)d_in[0];
    const float* hidden = (const float*)d_in[1];
    const int*   src    = (const int*)d_in[2];
    const int*   dst    = (const int*)d_in[3];
    const float* ew     = (const float*)d_in[4];
    const float* Wself  = (const float*)d_in[5];
    const float* Wneigh = (const float*)d_in[6];
    const float* bias   = (const float*)d_in[7];
    float* out = (float*)d_out;

    int N = in_sizes[0] / F;  // 50000
    int E = in_sizes[2];      // 800000
    size_t NF = (size_t)N * F;
    int NK = N * 16;          // composite key space: dst*16 + src-bucket

    char* p = (char*)d_ws;
    auto alloc = [&](size_t bytes) { char* r = p; p += (bytes + 255) & ~255ull; return r; };
    unsigned short* xh0    = (unsigned short*)alloc(2 * NF * 2);  // [N][256] x|h layer0
    unsigned short* xh1    = (unsigned short*)alloc(2 * NF * 2);  // [N][256] x|h layer1
    unsigned short* agg_xb = (unsigned short*)alloc(NF * 2);
    unsigned short* agg_hb = (unsigned short*)alloc(NF * 2);
    unsigned short* agg_rb = (unsigned short*)alloc(NF * 2);
    unsigned short* rhb    = (unsigned short*)alloc(NF * 2);
    float*          u      = (float*)alloc(NF * 4);
    unsigned short* W1b    = (unsigned short*)alloc(2 * 64 * 256 * 8 * 2);
    unsigned short* W2b    = (unsigned short*)alloc(2 * 64 * 128 * 8 * 2);
    int2*           es     = (int2*)alloc((size_t)E * 8);
    int*            cnt2   = (int*)alloc((size_t)NK * 4);
    int*            offs2  = (int*)alloc(((size_t)NK + 1) * 4);
    int*            cur2   = (int*)alloc((size_t)NK * 4);
    int*            bsum   = (int*)alloc(1024 * 4);

    pack_w_bf16<<<dim3(1536), dim3(256), 0, stream>>>(Wself, Wneigh, W1b, W2b);
    int n4 = (int)(NF / 4);
    cvt_all<<<dim3((3 * n4 + 255) / 256), dim3(256), 0, stream>>>(x, hidden, xh0, xh1, n4, NF);

    hipMemsetAsync(cnt2, 0, (size_t)NK * sizeof(int), stream);
    int eBlocks = (E + 255) / 256;
    hist_key<<<dim3(eBlocks), dim3(256), 0, stream>>>(src, dst, cnt2, E);
    int nb = (NK + 1023) / 1024;  // 782 (<= 1024)
    scan_blk<<<dim3(nb), dim3(1024), 0, stream>>>(cnt2, offs2, bsum, NK);
    scan_tops<<<dim3(1), dim3(1024), 0, stream>>>(bsum, nb, offs2 + NK);
    scan_add<<<dim3(nb), dim3(1024), 0, stream>>>(bsum, offs2, cur2, NK);
    scatter_edges<<<dim3(eBlocks), dim3(256), 0, stream>>>(src, dst, ew, cur2, es, E);

    float* out_x  = out;
    float* out_h1 = out + NF;
    float* out_h2 = out + 2 * NF;

    int aggBlocks = (N + 7) / 8;
    int mBlocks = (N + 63) / 64;
    for (int l = 0; l < NLAYERS; ++l) {
        unsigned short* xhL = (l == 0) ? xh0 : xh1;
        const float* hL = hidden + (size_t)l * NF;
        const float* biasL = bias + (size_t)l * 384;

        agg_csr2_i<<<dim3(aggBlocks), dim3(256), 0, stream>>>(xhL, es, offs2,
                                                              agg_xb, agg_hb, N);

        gemm_ru<<<dim3(mBlocks, 2), dim3(256), 0, stream>>>(
            xhL, agg_xb, agg_hb,
            W1b + (size_t)l * 64 * 256 * 8, biasL, hL,
            rhb, u, N);

        agg_csr1_b<<<dim3(aggBlocks), dim3(256), 0, stream>>>(rhb, es, offs2, agg_rb, N);

        float* o1 = (l == 0) ? out_h1 : out_h2;
        float* o2 = (l == NLAYERS - 1) ? out_x : nullptr;
        // l==0: outb -> xh1 cols 0:128 (stride 256, obsh=8) = next layer's x.
        // l==1: outb dead; reuse agg_rb (each block writes only its own rows,
        //       after its last staged read of them) with obsh=7.
        unsigned short* obN = (l == 0) ? xh1 : agg_rb;
        int obsh = (l == 0) ? 8 : 7;
        gemm_c<<<dim3(mBlocks), dim3(256), 0, stream>>>(
            xhL, rhb, agg_xb, agg_rb,
            W2b + (size_t)l * 64 * 128 * 8, biasL + 256, hL, u,
            obN, o1, o2, obsh, N);
    }
}

// Round 7
// 588.380 us; speedup vs baseline: 1.2155x; 1.0011x over previous
//
#include <hip/hip_runtime.h>
#include <math.h>

#define F 128
#define NLAYERS 2

typedef __attribute__((ext_vector_type(8))) short bf16x8s;
typedef __attribute__((ext_vector_type(8))) unsigned short u16x8;
typedef __attribute__((ext_vector_type(4))) float f32x4;

__device__ __forceinline__ float sigmoidf_(float x) { return 1.0f / (1.0f + expf(-x)); }

__device__ __forceinline__ unsigned short f2bf(float f) {
    unsigned int u = __float_as_uint(f);
    u += 0x7fffu + ((u >> 16) & 1u);  // RNE
    return (unsigned short)(u >> 16);
}
__device__ __forceinline__ float bf2f(unsigned short s) {
    return __uint_as_float(((unsigned int)s) << 16);
}

// ---------------------------------------------------------------------------
// Weight pack: f32 [L][3][256][128] -> bf16 k-octet layout.
//  W1b [L][64][256][8]: gates (r|u) as 256 cols, K=512 parts (x,h,agg_x,agg_h)
//  W2b [L][64][128][8]: gate c, K parts (x, rh, agg_x, agg_rh)
// ---------------------------------------------------------------------------
__global__ void pack_w_bf16(const float* __restrict__ Ws, const float* __restrict__ Wn,
                            unsigned short* __restrict__ W1b, unsigned short* __restrict__ W2b) {
    int t = blockIdx.x * blockDim.x + threadIdx.x;
    const int n1 = 2 * 64 * 256 * 8;  // 262144
    if (t < n1) {
        int j = t & 7, n = (t >> 3) & 255, ko = (t >> 11) & 63, l = t >> 17;
        int k = ko * 8 + j;
        int p = k >> 7, r = k & 127, g = n >> 7, c = n & 127;
        const float* W = (p < 2) ? Ws : Wn;
        W1b[t] = f2bf(W[(((l * 3 + g) * 256) + ((p & 1) * 128 + r)) * 128 + c]);
    } else {
        int t2 = t - n1;
        if (t2 >= 2 * 64 * 128 * 8) return;
        int j = t2 & 7, n = (t2 >> 3) & 127, ko = (t2 >> 10) & 63, l = t2 >> 16;
        int k = ko * 8 + j;
        int p = k >> 7, r = k & 127;
        const float* W = (p < 2) ? Ws : Wn;
        W2b[t2] = f2bf(W[(((l * 3 + 2) * 256) + ((p & 1) * 128 + r)) * 128 + n]);
    }
}

// Fused f32 -> bf16 interleave: x -> xh0[:,0:128], h0 -> xh0[:,128:256],
// h1 -> xh1[:,128:256]. Each t handles 4 floats.
__global__ void cvt_all(const float* __restrict__ x, const float* __restrict__ hidden,
                        unsigned short* __restrict__ xh0, unsigned short* __restrict__ xh1,
                        int n4, size_t NF) {
    int t = blockIdx.x * blockDim.x + threadIdx.x;
    const float* in;
    unsigned short* out;
    int tt;
    if (t < n4) { in = x; out = xh0; tt = t; }
    else if (t < 2 * n4) { in = hidden; out = xh0 + 128; tt = t - n4; }
    else if (t < 3 * n4) { in = hidden + NF; out = xh1 + 128; tt = t - 2 * n4; }
    else return;
    float4 v = reinterpret_cast<const float4*>(in)[tt];
    ushort4 o;
    o.x = f2bf(v.x); o.y = f2bf(v.y); o.z = f2bf(v.z); o.w = f2bf(v.w);
    *reinterpret_cast<ushort4*>(out + (((size_t)(tt >> 5)) << 8) + ((tt & 31) << 2)) = o;
}

// ---------------------------------------------------------------------------
// CSR build with composite key = dst*16 + (src>>12): per-dst edge lists come
// out bucketed by src range -> all blocks walk the xh table front-to-back in
// loose lockstep -> L2-resident working set.
// ---------------------------------------------------------------------------
__global__ void hist_key(const int* __restrict__ src, const int* __restrict__ dst,
                         int* __restrict__ cnt, int E) {
    int e = blockIdx.x * blockDim.x + threadIdx.x;
    if (e < E) atomicAdd(&cnt[(dst[e] << 4) + (src[e] >> 12)], 1);
}

__global__ __launch_bounds__(1024) void scan_blk(const int* __restrict__ cnt,
                                                 int* __restrict__ offs,
                                                 int* __restrict__ bsum, int n) {
    __shared__ int wsum[16];
    int tid = threadIdx.x, lane = tid & 63, wid = tid >> 6;
    int i = blockIdx.x * 1024 + tid;
    int v = (i < n) ? cnt[i] : 0;
    int incl = v;
#pragma unroll
    for (int off = 1; off < 64; off <<= 1) {
        int t = __shfl_up(incl, off, 64);
        if (lane >= off) incl += t;
    }
    if (lane == 63) wsum[wid] = incl;
    __syncthreads();
    if (wid == 0) {
        int s = (lane < 16) ? wsum[lane] : 0;
#pragma unroll
        for (int off = 1; off < 16; off <<= 1) {
            int t = __shfl_up(s, off, 64);
            if (lane >= off) s += t;
        }
        if (lane < 16) wsum[lane] = s;
    }
    __syncthreads();
    int wbase = (wid > 0) ? wsum[wid - 1] : 0;
    if (i < n) offs[i] = wbase + incl - v;
    if (tid == 1023) bsum[blockIdx.x] = wbase + incl;
}

__global__ __launch_bounds__(1024) void scan_tops(int* __restrict__ bsum, int nb,
                                                  int* __restrict__ total_out) {
    __shared__ int wsum[16];
    int tid = threadIdx.x, lane = tid & 63, wid = tid >> 6;
    int v = (tid < nb) ? bsum[tid] : 0;
    int incl = v;
#pragma unroll
    for (int off = 1; off < 64; off <<= 1) {
        int t = __shfl_up(incl, off, 64);
        if (lane >= off) incl += t;
    }
    if (lane == 63) wsum[wid] = incl;
    __syncthreads();
    if (wid == 0) {
        int s = (lane < 16) ? wsum[lane] : 0;
#pragma unroll
        for (int off = 1; off < 16; off <<= 1) {
            int t = __shfl_up(s, off, 64);
            if (lane >= off) s += t;
        }
        if (lane < 16) wsum[lane] = s;
    }
    __syncthreads();
    int wbase = (wid > 0) ? wsum[wid - 1] : 0;
    if (tid < nb) bsum[tid] = wbase + incl - v;
    if (tid == 1023) *total_out = wbase + incl;
}

__global__ __launch_bounds__(1024) void scan_add(const int* __restrict__ bsum,
                                                 int* __restrict__ offs,
                                                 int* __restrict__ cursor, int n) {
    int i = blockIdx.x * 1024 + threadIdx.x;
    if (i >= n) return;
    int o = offs[i] + bsum[blockIdx.x];
    offs[i] = o;
    cursor[i] = o;
}

__global__ void scatter_edges(const int* __restrict__ src, const int* __restrict__ dst,
                              const float* __restrict__ ew, int* __restrict__ cursor,
                              int2* __restrict__ es, int E) {
    int e = blockIdx.x * blockDim.x + threadIdx.x;
    if (e >= E) return;
    int s = src[e];
    int key = (dst[e] << 4) + (s >> 12);
    int p = atomicAdd(&cursor[key], 1);
    es[p] = make_int2(s, __float_as_int(ew[e]));
}

// ---------------------------------------------------------------------------
// CSR aggregation over interleaved xh[N][256] bf16: 32 lanes/node, each lane
// one 16B (ushort8) gather per edge. Node segment = offs2[n*16 .. n*16+16).
// ---------------------------------------------------------------------------
__global__ __launch_bounds__(256) void agg_csr2_i(
    const unsigned short* __restrict__ XH,
    const int2* __restrict__ es, const int* __restrict__ offs2,
    unsigned short* __restrict__ agg0, unsigned short* __restrict__ agg1, int N) {
    int node = blockIdx.x * 8 + (threadIdx.x >> 5);
    if (node >= N) return;
    int lane = threadIdx.x & 31;
    int beg = offs2[node << 4], end = offs2[(node << 4) + 16];
    float a0[8] = {0, 0, 0, 0, 0, 0, 0, 0};
    float a1[8] = {0, 0, 0, 0, 0, 0, 0, 0};
    int loff = lane << 3;
    int i = beg;
    for (; i + 3 < end; i += 4) {
        int2 e0 = es[i], e1 = es[i + 1], e2 = es[i + 2], e3 = es[i + 3];
        u16x8 v0 = *reinterpret_cast<const u16x8*>(XH + (((size_t)e0.x) << 8) + loff);
        u16x8 v1 = *reinterpret_cast<const u16x8*>(XH + (((size_t)e1.x) << 8) + loff);
        u16x8 v2 = *reinterpret_cast<const u16x8*>(XH + (((size_t)e2.x) << 8) + loff);
        u16x8 v3 = *reinterpret_cast<const u16x8*>(XH + (((size_t)e3.x) << 8) + loff);
        float w0 = __int_as_float(e0.y), w1 = __int_as_float(e1.y);
        float w2 = __int_as_float(e2.y), w3 = __int_as_float(e3.y);
#pragma unroll
        for (int j = 0; j < 8; ++j) {
            a0[j] += w0 * bf2f(v0[j]);
            a1[j] += w1 * bf2f(v1[j]);
            a0[j] += w2 * bf2f(v2[j]);
            a1[j] += w3 * bf2f(v3[j]);
        }
    }
    for (; i < end; ++i) {
        int2 e0 = es[i];
        float w0 = __int_as_float(e0.y);
        u16x8 v0 = *reinterpret_cast<const u16x8*>(XH + (((size_t)e0.x) << 8) + loff);
#pragma unroll
        for (int j = 0; j < 8; ++j) a0[j] += w0 * bf2f(v0[j]);
    }
    u16x8 o;
#pragma unroll
    for (int j = 0; j < 8; ++j) o[j] = f2bf(a0[j] + a1[j]);
    unsigned short* op = (lane < 16)
        ? (agg0 + (((size_t)node) << 7) + (lane << 3))
        : (agg1 + (((size_t)node) << 7) + ((lane & 15) << 3));
    *reinterpret_cast<u16x8*>(op) = o;
}

// Single-table CSR aggregation (rh, [N][128] bf16): 32 lanes x 8B, unroll-4.
__global__ __launch_bounds__(256) void agg_csr1_b(
    const unsigned short* __restrict__ V0,
    const int2* __restrict__ es, const int* __restrict__ offs2,
    unsigned short* __restrict__ agg0, int N) {
    int node = blockIdx.x * 8 + (threadIdx.x >> 5);
    if (node >= N) return;
    int lane = threadIdx.x & 31;
    int beg = offs2[node << 4], end = offs2[(node << 4) + 16];
    float p0[4] = {0, 0, 0, 0}, p1[4] = {0, 0, 0, 0};
    int loff = lane << 2;
    int i = beg;
    for (; i + 3 < end; i += 4) {
        int2 e0 = es[i], e1 = es[i + 1], e2 = es[i + 2], e3 = es[i + 3];
        ushort4 x0 = *reinterpret_cast<const ushort4*>(V0 + (((size_t)e0.x) << 7) + loff);
        ushort4 x1 = *reinterpret_cast<const ushort4*>(V0 + (((size_t)e1.x) << 7) + loff);
        ushort4 x2 = *reinterpret_cast<const ushort4*>(V0 + (((size_t)e2.x) << 7) + loff);
        ushort4 x3 = *reinterpret_cast<const ushort4*>(V0 + (((size_t)e3.x) << 7) + loff);
        float w0 = __int_as_float(e0.y), w1 = __int_as_float(e1.y);
        float w2 = __int_as_float(e2.y), w3 = __int_as_float(e3.y);
        p0[0] += w0 * bf2f(x0.x); p0[1] += w0 * bf2f(x0.y);
        p0[2] += w0 * bf2f(x0.z); p0[3] += w0 * bf2f(x0.w);
        p1[0] += w1 * bf2f(x1.x); p1[1] += w1 * bf2f(x1.y);
        p1[2] += w1 * bf2f(x1.z); p1[3] += w1 * bf2f(x1.w);
        p0[0] += w2 * bf2f(x2.x); p0[1] += w2 * bf2f(x2.y);
        p0[2] += w2 * bf2f(x2.z); p0[3] += w2 * bf2f(x2.w);
        p1[0] += w3 * bf2f(x3.x); p1[1] += w3 * bf2f(x3.y);
        p1[2] += w3 * bf2f(x3.z); p1[3] += w3 * bf2f(x3.w);
    }
    for (; i < end; ++i) {
        int2 e0 = es[i];
        float w0 = __int_as_float(e0.y);
        ushort4 x0 = *reinterpret_cast<const ushort4*>(V0 + (((size_t)e0.x) << 7) + loff);
        p0[0] += w0 * bf2f(x0.x); p0[1] += w0 * bf2f(x0.y);
        p0[2] += w0 * bf2f(x0.z); p0[3] += w0 * bf2f(x0.w);
    }
    size_t ob = (((size_t)node) << 7) + loff;
    ushort4 o0;
    o0.x = f2bf(p0[0] + p1[0]); o0.y = f2bf(p0[1] + p1[1]);
    o0.z = f2bf(p0[2] + p1[2]); o0.w = f2bf(p0[3] + p1[3]);
    *reinterpret_cast<ushort4*>(agg0 + ob) = o0;
}

// ---------------------------------------------------------------------------
// GEMM gates r|u: 128x128 tile, y-grid=2 over 256 cols, K=512, 512 threads,
// 8 waves (2x4), wave tile 64x32 (acc 4x2), double-buffered LDS (32KB).
// A parts: x,h from xh (stride 256), aggx/aggh (stride 128). B = W1b k-octet.
// Epilogue: col<128 -> rhb = bf16(sigmoid*h); col>=128 -> u = sigmoid (f32)
// ---------------------------------------------------------------------------
__global__ __launch_bounds__(512) void gemm_ru(
    const unsigned short* __restrict__ XH,
    const unsigned short* __restrict__ AGGX, const unsigned short* __restrict__ AGGH,
    const unsigned short* __restrict__ Wb, const float* __restrict__ bias,
    const float* __restrict__ hfull,
    unsigned short* __restrict__ rhb, float* __restrict__ u, int N) {
    __shared__ __align__(16) unsigned short Als[2][4 * 128 * 8];  // 8KB x2
    __shared__ __align__(16) unsigned short Bls[2][4 * 128 * 8];  // 8KB x2

    int tid = threadIdx.x;
    int row0 = blockIdx.x * 128;
    int n0c = blockIdx.y * 128;
    int lane = tid & 63;
    int w = tid >> 6;               // 8 waves
    int wrow = (w & 1) << 6;        // 0 / 64
    int wcol = (w >> 1) << 5;       // 0 / 32 / 64 / 96
    int quad = lane >> 4, l16 = lane & 15;

    f32x4 acc[4][2];
    const f32x4 z4 = {0.f, 0.f, 0.f, 0.f};
#pragma unroll
    for (int mt = 0; mt < 4; ++mt)
#pragma unroll
        for (int nt = 0; nt < 2; ++nt) acc[mt][nt] = z4;

    int mA = tid & 127, qA = tid >> 7;  // staging: one (q,m) pair per thread
    int growA = row0 + mA;
    if (growA >= N) growA = N - 1;
    int nB = tid & 127, qB = tid >> 7;

    auto stage = [&](int ks, int buf) {
        int p = ks >> 7;
        const unsigned short* ga =
            (p == 0) ? (XH + (size_t)growA * 256 + (ks & 127) + (qA << 3))
          : (p == 1) ? (XH + (size_t)growA * 256 + 128 + (ks & 127) + (qA << 3))
          : (p == 2) ? (AGGX + ((size_t)growA << 7) + (ks & 127) + (qA << 3))
                     : (AGGH + ((size_t)growA << 7) + (ks & 127) + (qA << 3));
        __builtin_amdgcn_global_load_lds(
            (const __attribute__((address_space(1))) void*)ga,
            (__attribute__((address_space(3))) void*)&Als[buf][((qA << 7) + mA) << 3], 16, 0, 0);
        int koG = (ks >> 3) + qB;
        const unsigned short* gb = Wb + ((size_t)(koG * 256 + n0c + nB) << 3);
        __builtin_amdgcn_global_load_lds(
            (const __attribute__((address_space(1))) void*)gb,
            (__attribute__((address_space(3))) void*)&Bls[buf][((qB << 7) + nB) << 3], 16, 0, 0);
    };

    stage(0, 0);
    __syncthreads();
    int buf = 0;
    for (int ks = 0; ks < 512; ks += 32, buf ^= 1) {
        if (ks + 32 < 512) stage(ks + 32, buf ^ 1);

        bf16x8s af[4], bfr[2];
#pragma unroll
        for (int mt = 0; mt < 4; ++mt)
            af[mt] = *reinterpret_cast<const bf16x8s*>(
                &Als[buf][((quad << 7) + wrow + (mt << 4) + l16) << 3]);
#pragma unroll
        for (int nt = 0; nt < 2; ++nt)
            bfr[nt] = *reinterpret_cast<const bf16x8s*>(
                &Bls[buf][((quad << 7) + wcol + (nt << 4) + l16) << 3]);
#pragma unroll
        for (int mt = 0; mt < 4; ++mt)
#pragma unroll
            for (int nt = 0; nt < 2; ++nt)
                acc[mt][nt] = __builtin_amdgcn_mfma_f32_16x16x32_bf16(
                    af[mt], bfr[nt], acc[mt][nt], 0, 0, 0);
        __syncthreads();
    }

#pragma unroll
    for (int mt = 0; mt < 4; ++mt) {
#pragma unroll
        for (int reg = 0; reg < 4; ++reg) {
            int row = row0 + wrow + (mt << 4) + (quad << 2) + reg;
            if (row >= N) continue;
#pragma unroll
            for (int nt = 0; nt < 2; ++nt) {
                int col = n0c + wcol + (nt << 4) + l16;
                float val = acc[mt][nt][reg] + bias[col];
                float sg = sigmoidf_(val);
                int c = col & 127;
                size_t o = ((size_t)row << 7) + c;
                if (col < 128)
                    rhb[o] = f2bf(sg * hfull[o]);   // rh = r*h (bf16)
                else
                    u[o] = sg;                       // u (f32)
            }
        }
    }
}

// ---------------------------------------------------------------------------
// GEMM gate c: 128x128 tile, K=512, 512 threads, 8 waves (2x4), acc 4x2.
// A parts: x (xh stride 256), rh (128), aggx (128), agg_rh (128). B = W2b.
// Epilogue: c = sigmoid; hn = u*h+(1-u)*c -> outf (+outf2); outb = bf16(hn)
// with row shift obsh (8 -> next xh cols 0:128, 7 -> plain 128-col table).
// ---------------------------------------------------------------------------
__global__ __launch_bounds__(512) void gemm_c(
    const unsigned short* __restrict__ XH, const unsigned short* __restrict__ RHB,
    const unsigned short* __restrict__ AGGX, const unsigned short* __restrict__ AGGR,
    const unsigned short* __restrict__ Wb, const float* __restrict__ bias,
    const float* __restrict__ hfull, const float* __restrict__ uin,
    unsigned short* __restrict__ outb, float* __restrict__ outf,
    float* __restrict__ outf2, int obsh, int N) {
    __shared__ __align__(16) unsigned short Als[2][4 * 128 * 8];  // 8KB x2
    __shared__ __align__(16) unsigned short Bls[2][4 * 128 * 8];  // 8KB x2

    int tid = threadIdx.x;
    int row0 = blockIdx.x * 128;
    int lane = tid & 63;
    int w = tid >> 6;
    int wrow = (w & 1) << 6;
    int wcol = (w >> 1) << 5;
    int quad = lane >> 4, l16 = lane & 15;

    f32x4 acc[4][2];
    const f32x4 z4 = {0.f, 0.f, 0.f, 0.f};
#pragma unroll
    for (int mt = 0; mt < 4; ++mt)
#pragma unroll
        for (int nt = 0; nt < 2; ++nt) acc[mt][nt] = z4;

    int mA = tid & 127, qA = tid >> 7;
    int growA = row0 + mA;
    if (growA >= N) growA = N - 1;
    int nB = tid & 127, qB = tid >> 7;

    auto stage = [&](int ks, int buf) {
        int p = ks >> 7;
        const unsigned short* ga =
            (p == 0) ? (XH + (size_t)growA * 256 + (ks & 127) + (qA << 3))
          : (p == 1) ? (RHB + ((size_t)growA << 7) + (ks & 127) + (qA << 3))
          : (p == 2) ? (AGGX + ((size_t)growA << 7) + (ks & 127) + (qA << 3))
                     : (AGGR + ((size_t)growA << 7) + (ks & 127) + (qA << 3));
        __builtin_amdgcn_global_load_lds(
            (const __attribute__((address_space(1))) void*)ga,
            (__attribute__((address_space(3))) void*)&Als[buf][((qA << 7) + mA) << 3], 16, 0, 0);
        int koG = (ks >> 3) + qB;
        const unsigned short* gb = Wb + ((size_t)(koG * 128 + nB) << 3);
        __builtin_amdgcn_global_load_lds(
            (const __attribute__((address_space(1))) void*)gb,
            (__attribute__((address_space(3))) void*)&Bls[buf][((qB << 7) + nB) << 3], 16, 0, 0);
    };

    stage(0, 0);
    __syncthreads();
    int buf = 0;
    for (int ks = 0; ks < 512; ks += 32, buf ^= 1) {
        if (ks + 32 < 512) stage(ks + 32, buf ^ 1);

        bf16x8s af[4], bfr[2];
#pragma unroll
        for (int mt = 0; mt < 4; ++mt)
            af[mt] = *reinterpret_cast<const bf16x8s*>(
                &Als[buf][((quad << 7) + wrow + (mt << 4) + l16) << 3]);
#pragma unroll
        for (int nt = 0; nt < 2; ++nt)
            bfr[nt] = *reinterpret_cast<const bf16x8s*>(
                &Bls[buf][((quad << 7) + wcol + (nt << 4) + l16) << 3]);
#pragma unroll
        for (int mt = 0; mt < 4; ++mt)
#pragma unroll
            for (int nt = 0; nt < 2; ++nt)
                acc[mt][nt] = __builtin_amdgcn_mfma_f32_16x16x32_bf16(
                    af[mt], bfr[nt], acc[mt][nt], 0, 0, 0);
        __syncthreads();
    }

#pragma unroll
    for (int mt = 0; mt < 4; ++mt) {
#pragma unroll
        for (int reg = 0; reg < 4; ++reg) {
            int row = row0 + wrow + (mt << 4) + (quad << 2) + reg;
            if (row >= N) continue;
#pragma unroll
            for (int nt = 0; nt < 2; ++nt) {
                int col = wcol + (nt << 4) + l16;
                float val = acc[mt][nt][reg] + bias[col];
                float cv = sigmoidf_(val);
                size_t o = ((size_t)row << 7) + col;
                float uu = uin[o];
                float hh = hfull[o];
                float hn = uu * hh + (1.0f - uu) * cv;
                outf[o] = hn;
                if (outf2) outf2[o] = hn;
                outb[((size_t)row << obsh) + col] = f2bf(hn);  // next layer's x
            }
        }
    }
}

// ---------------------------------------------------------------------------
extern "C" void kernel_launch(void* const* d_in, const int* in_sizes, int n_in,
                              void* d_out, int out_size, void* d_ws, size_t ws_size,
                              hipStream_t stream) {
    const float* x      = (const float*)d_in[0];
    const float* hidden = (const float*)d_in[1];
    const int*   src    = (const int*)d_in[2];
    const int*   dst    = (const int*)d_in[3];
    const float* ew     = (const float*)d_in[4];
    const float* Wself  = (const float*)d_in[5];
    const float* Wneigh = (const float*)d_in[6];
    const float* bias   = (const float*)d_in[7];
    float* out = (float*)d_out;

    int N = in_sizes[0] / F;  // 50000
    int E = in_sizes[2];      // 800000
    size_t NF = (size_t)N * F;
    int NK = N * 16;          // composite key space: dst*16 + src-bucket

    char* p = (char*)d_ws;
    auto alloc = [&](size_t bytes) { char* r = p; p += (bytes + 255) & ~255ull; return r; };
    unsigned short* xh0    = (unsigned short*)alloc(2 * NF * 2);  // [N][256] x|h layer0
    unsigned short* xh1    = (unsigned short*)alloc(2 * NF * 2);  // [N][256] x|h layer1
    unsigned short* agg_xb = (unsigned short*)alloc(NF * 2);
    unsigned short* agg_hb = (unsigned short*)alloc(NF * 2);
    unsigned short* agg_rb = (unsigned short*)alloc(NF * 2);
    unsigned short* rhb    = (unsigned short*)alloc(NF * 2);
    float*          u      = (float*)alloc(NF * 4);
    unsigned short* W1b    = (unsigned short*)alloc(2 * 64 * 256 * 8 * 2);
    unsigned short* W2b    = (unsigned short*)alloc(2 * 64 * 128 * 8 * 2);
    int2*           es     = (int2*)alloc((size_t)E * 8);
    int*            cnt2   = (int*)alloc((size_t)NK * 4);
    int*            offs2  = (int*)alloc(((size_t)NK + 1) * 4);
    int*            cur2   = (int*)alloc((size_t)NK * 4);
    int*            bsum   = (int*)alloc(1024 * 4);

    pack_w_bf16<<<dim3(1536), dim3(256), 0, stream>>>(Wself, Wneigh, W1b, W2b);
    int n4 = (int)(NF / 4);
    cvt_all<<<dim3((3 * n4 + 255) / 256), dim3(256), 0, stream>>>(x, hidden, xh0, xh1, n4, NF);

    hipMemsetAsync(cnt2, 0, (size_t)NK * sizeof(int), stream);
    int eBlocks = (E + 255) / 256;
    hist_key<<<dim3(eBlocks), dim3(256), 0, stream>>>(src, dst, cnt2, E);
    int nb = (NK + 1023) / 1024;  // 782 (<= 1024)
    scan_blk<<<dim3(nb), dim3(1024), 0, stream>>>(cnt2, offs2, bsum, NK);
    scan_tops<<<dim3(1), dim3(1024), 0, stream>>>(bsum, nb, offs2 + NK);
    scan_add<<<dim3(nb), dim3(1024), 0, stream>>>(bsum, offs2, cur2, NK);
    scatter_edges<<<dim3(eBlocks), dim3(256), 0, stream>>>(src, dst, ew, cur2, es, E);

    float* out_x  = out;
    float* out_h1 = out + NF;
    float* out_h2 = out + 2 * NF;

    int aggBlocks = (N + 7) / 8;
    int mBlocks = (N + 127) / 128;  // 391
    for (int l = 0; l < NLAYERS; ++l) {
        unsigned short* xhL = (l == 0) ? xh0 : xh1;
        const float* hL = hidden + (size_t)l * NF;
        const float* biasL = bias + (size_t)l * 384;

        agg_csr2_i<<<dim3(aggBlocks), dim3(256), 0, stream>>>(xhL, es, offs2,
                                                              agg_xb, agg_hb, N);

        gemm_ru<<<dim3(mBlocks, 2), dim3(512), 0, stream>>>(
            xhL, agg_xb, agg_hb,
            W1b + (size_t)l * 64 * 256 * 8, biasL, hL,
            rhb, u, N);

        agg_csr1_b<<<dim3(aggBlocks), dim3(256), 0, stream>>>(rhb, es, offs2, agg_rb, N);

        float* o1 = (l == 0) ? out_h1 : out_h2;
        float* o2 = (l == NLAYERS - 1) ? out_x : nullptr;
        // l==0: outb -> xh1 cols 0:128 (stride 256, obsh=8) = next layer's x.
        // l==1: outb dead; reuse agg_rb (each block writes only its own rows,
        //       after its last staged read of them) with obsh=7.
        unsigned short* obN = (l == 0) ? xh1 : agg_rb;
        int obsh = (l == 0) ? 8 : 7;
        gemm_c<<<dim3(mBlocks), dim3(512), 0, stream>>>(
            xhL, rhb, agg_xb, agg_rb,
            W2b + (size_t)l * 64 * 128 * 8, biasL + 256, hL, u,
            obN, o1, o2, obsh, N);
    }
}